// Round 4
// baseline (1910.048 us; speedup 1.0000x reference)
//
#include <hip/hip_runtime.h>
#include <hip/hip_bf16.h>

#define MDIM 4096      // B*S tokens
#define DDIM 512
#define HHEADS 8
#define SLEN 2048
#define TDIM 256
#define SPLIT 4
#define NBLK 512
#define NTHR 256
#define LDT 66
#define EXPC 0.1803368801111244f   // 0.125 * log2(e)

typedef __attribute__((ext_vector_type(8))) short short8;
typedef __attribute__((ext_vector_type(16))) float f32x16;

__device__ __forceinline__ unsigned short f2bf(float f) {
    union { __hip_bfloat16 h; unsigned short u; } c;
    c.h = __float2bfloat16(f);
    return c.u;
}
__device__ __forceinline__ float bf2f(short s) {
    return __uint_as_float((unsigned)(unsigned short)s << 16);
}

// LDS union across stages; max member 25.3 KB -> 2 blocks/CU guaranteed.
union Shm {
    struct { short As[128 * LDT]; short Bs[64 * LDT]; } g;   // gemm/qkv
    struct { short Ks[64 * 72]; short Vs[64 * 72]; } st;     // attn
};

struct KParams {
    const float *x, *Wq, *bq, *Wk, *bk, *Wv, *bv, *Wo, *bo, *g1, *be1;
    const float *W1, *b1, *W2, *b2, *g2, *be2, *Wp, *bp;
    float* out;
    short *xbf, *Qbuf, *Kbuf, *Vtbuf, *hcbf, *hidbf, *Opart;
    float *y, *lpart;
    short *Wqt, *Wkt, *Wvt, *Wot, *W1t, *W2t, *Wpt;
    unsigned* bar;
};

// Grid barrier v2: arrive = one ACQ_REL RMW; spin = pure coherent LOADS
// (no RMW serialization — R3's 30us/barrier bug). Generation-based release.
// SAFE: 512 blocks, 256 thr, <=256 VGPR (launch_bounds), 25.3KB LDS
// -> 2 blocks/CU x 256 CUs = full co-residency.
__device__ __forceinline__ void gridbar(unsigned* bar) {
    __syncthreads();
    if (threadIdx.x == 0) {
        unsigned gen = __hip_atomic_load(&bar[1], __ATOMIC_RELAXED, __HIP_MEMORY_SCOPE_AGENT);
        unsigned old = __hip_atomic_fetch_add(&bar[0], 1u, __ATOMIC_ACQ_REL, __HIP_MEMORY_SCOPE_AGENT);
        if (old == (unsigned)NBLK - 1u) {
            __hip_atomic_store(&bar[0], 0u, __ATOMIC_RELAXED, __HIP_MEMORY_SCOPE_AGENT);
            __threadfence();
            __hip_atomic_fetch_add(&bar[1], 1u, __ATOMIC_RELEASE, __HIP_MEMORY_SCOPE_AGENT);
        } else {
            while (__hip_atomic_load(&bar[1], __ATOMIC_ACQUIRE, __HIP_MEMORY_SCOPE_AGENT) == gen)
                __builtin_amdgcn_s_sleep(1);
        }
        __threadfence();
    }
    __syncthreads();
}

// ---------------------------------------------------------------------------
// prep (grid-stride): weights fp32 -> bf16 transposed; x -> bf16.
// ---------------------------------------------------------------------------
#define N1 524288
#define N2 524288
#define NP 131072
#define PREP_TOT (3L * N1 + 3L * N2 + NP + 2097152L)

__device__ void prep_stage(const KParams& P)
{
    for (long idx0 = (long)blockIdx.x * NTHR + threadIdx.x; idx0 < PREP_TOT;
         idx0 += (long)NBLK * NTHR) {
        long idx = idx0;
        if (idx < 3L * N1) {
            int t = (int)(idx / N1);
            int r = (int)(idx % N1);
            int a = r & 63, k = (r >> 6) & 511, hh = r >> 15;
            const float* src = (t == 0) ? P.Wq : (t == 1) ? P.Wk : P.Wv;
            short* dst = (t == 0) ? P.Wqt : (t == 1) ? P.Wkt : P.Wvt;
            dst[((size_t)hh << 15) + (a << 9) + k] = (short)f2bf(src[r]);
            continue;
        }
        idx -= 3L * N1;
        if (idx < 3L * N2) {
            int t = (int)(idx / N2);
            int r = (int)(idx % N2);
            int n = r & 511, k = (r >> 9) & 511, i = r >> 18;
            const float* src = (t == 0) ? P.Wo : (t == 1) ? P.W1 : P.W2;
            short* dst = (t == 0) ? P.Wot : (t == 1) ? P.W1t : P.W2t;
            dst[((size_t)i << 18) + (n << 9) + k] = (short)f2bf(src[r]);
            continue;
        }
        idx -= 3L * N2;
        if (idx < NP) {
            int r = (int)idx;
            int n = r & 255, k = r >> 8;
            P.Wpt[n * 512 + k] = (short)f2bf(P.Wp[r]);
            continue;
        }
        idx -= NP;
        P.xbf[idx] = (short)f2bf(P.x[idx]);
    }
}

// ---------------------------------------------------------------------------
// gemm tile 64m x 64n (verbatim R0 gemm_bf body), 4 waves (2m x 2n).
// flags: 1=relu, 2=bf16 out.
// ---------------------------------------------------------------------------
__device__ void gemm_tile(Shm* shm,
    const short* __restrict__ A, const short* __restrict__ Bt,
    const float* __restrict__ bias, void* __restrict__ Cout,
    int N, int K, int flags, int m0, int n0)
{
    const int tid = threadIdx.x;
    const int wave = tid >> 6, lane = tid & 63;
    const int l31 = lane & 31, hi = lane >> 5;
    const int wm = wave >> 1, wn = wave & 1;

    f32x16 acc;
#pragma unroll
    for (int r = 0; r < 16; ++r) acc[r] = 0.f;

    const int sr = tid >> 2;          // 0..63
    const int sc = (tid & 3) * 16;    // short chunk

    for (int k0 = 0; k0 < K; k0 += 64) {
        __syncthreads();
        *(short8*)&shm->g.As[sr * LDT + sc]     = *(const short8*)&A[(size_t)(m0 + sr) * K + k0 + sc];
        *(short8*)&shm->g.As[sr * LDT + sc + 8] = *(const short8*)&A[(size_t)(m0 + sr) * K + k0 + sc + 8];
        *(short8*)&shm->g.Bs[sr * LDT + sc]     = *(const short8*)&Bt[(size_t)(n0 + sr) * K + k0 + sc];
        *(short8*)&shm->g.Bs[sr * LDT + sc + 8] = *(const short8*)&Bt[(size_t)(n0 + sr) * K + k0 + sc + 8];
        __syncthreads();

        short8 af[4], bfm[4];
#pragma unroll
        for (int ks = 0; ks < 4; ++ks) {
            af[ks]  = *(const short8*)&shm->g.As[(wm * 32 + l31) * LDT + ks * 16 + hi * 8];
            bfm[ks] = *(const short8*)&shm->g.Bs[(wn * 32 + l31) * LDT + ks * 16 + hi * 8];
        }
#pragma unroll
        for (int ks = 0; ks < 4; ++ks)
            acc = __builtin_amdgcn_mfma_f32_32x32x16_bf16(af[ks], bfm[ks], acc, 0, 0, 0);
    }

    const int col = n0 + wn * 32 + l31;
    const float bb = bias[col];
    const int rbase = m0 + wm * 32 + 4 * hi;
#pragma unroll
    for (int r = 0; r < 16; ++r) {
        int row = rbase + (r & 3) + 8 * (r >> 2);
        float v = acc[r] + bb;
        if (flags & 1) v = fmaxf(v, 0.f);
        if (flags & 2) ((short*)Cout)[(size_t)row * N + col] = (short)f2bf(v);
        else           ((float*)Cout)[(size_t)row * N + col] = v;
    }
}

// ---------------------------------------------------------------------------
// qkv tile (verbatim R1 qkv_bf body): 128m x 64a for one (which,h).
// ---------------------------------------------------------------------------
__device__ void qkv_tile(Shm* shm, const KParams& P, int ncol, int m0, int layer)
{
    const int tid = threadIdx.x;
    const int wave = tid >> 6, lane = tid & 63;
    const int l31 = lane & 31, hi = lane >> 5;
    const int wm = wave >> 1, wn = wave & 1;
    const int which = ncol >> 3, h = ncol & 7;
    const size_t wOff = (size_t)layer * 262144;

    const short* Bt = ((which == 0) ? P.Wqt : (which == 1) ? P.Wkt : P.Wvt)
                      + wOff + (size_t)h * 64 * 512;
    const float* bias = ((which == 0) ? P.bq : (which == 1) ? P.bk : P.bv)
                        + layer * 512 + h * 64;
    short* Out = (which == 0) ? P.Qbuf : (which == 1) ? P.Kbuf : P.Vtbuf;

    f32x16 acc[2];
#pragma unroll
    for (int ms = 0; ms < 2; ++ms)
#pragma unroll
        for (int r = 0; r < 16; ++r) acc[ms][r] = 0.f;

    const int sr = tid >> 3;
    const int sc = (tid & 7) * 8;

    for (int k0 = 0; k0 < 512; k0 += 64) {
        __syncthreads();
#pragma unroll
        for (int p = 0; p < 4; ++p)
            *(short8*)&shm->g.As[(p * 32 + sr) * LDT + sc] =
                *(const short8*)&P.xbf[(size_t)(m0 + p * 32 + sr) * 512 + k0 + sc];
#pragma unroll
        for (int p = 0; p < 2; ++p)
            *(short8*)&shm->g.Bs[(p * 32 + sr) * LDT + sc] =
                *(const short8*)&Bt[(size_t)(p * 32 + sr) * 512 + k0 + sc];
        __syncthreads();

        short8 af[2][4], bfm[4];
#pragma unroll
        for (int ms = 0; ms < 2; ++ms)
#pragma unroll
            for (int ks = 0; ks < 4; ++ks)
                af[ms][ks] = *(const short8*)&shm->g.As[(wm * 64 + ms * 32 + l31) * LDT + ks * 16 + hi * 8];
#pragma unroll
        for (int ks = 0; ks < 4; ++ks)
            bfm[ks] = *(const short8*)&shm->g.Bs[(wn * 32 + l31) * LDT + ks * 16 + hi * 8];
#pragma unroll
        for (int ms = 0; ms < 2; ++ms)
#pragma unroll
            for (int ks = 0; ks < 4; ++ks)
                acc[ms] = __builtin_amdgcn_mfma_f32_32x32x16_bf16(af[ms][ks], bfm[ks], acc[ms], 0, 0, 0);
    }

    const int a = wn * 32 + l31;
    const float bb = bias[a];
    const int b = m0 >> 11;
    const int sb = (m0 & (SLEN - 1)) + wm * 64;
    const int bh = b * HHEADS + h;

    if (which == 0) {
        short* Ob = Out + (size_t)bh * SLEN * 64;
#pragma unroll
        for (int ms = 0; ms < 2; ++ms)
#pragma unroll
            for (int r = 0; r < 16; ++r) {
                int s = sb + ms * 32 + (r & 3) + 8 * (r >> 2) + 4 * hi;
                Ob[(size_t)s * 64 + a] = (short)f2bf((acc[ms][r] + bb) * EXPC);
            }
    } else if (which == 1) {
        short* Ob = Out + (size_t)bh * SLEN * 64;
#pragma unroll
        for (int ms = 0; ms < 2; ++ms)
#pragma unroll
            for (int r = 0; r < 16; ++r) {
                int s = sb + ms * 32 + (r & 3) + 8 * (r >> 2) + 4 * hi;
                Ob[(size_t)s * 64 + a] = (short)f2bf(acc[ms][r] + bb);
            }
    } else {
        short* Ob = Out + ((size_t)bh * 64 + a) * SLEN;
#pragma unroll
        for (int ms = 0; ms < 2; ++ms)
#pragma unroll
            for (int g = 0; g < 4; ++g) {
                int s = sb + ms * 32 + 8 * g + 4 * hi;
                ushort4 w;
                w.x = f2bf(acc[ms][4 * g + 0] + bb);
                w.y = f2bf(acc[ms][4 * g + 1] + bb);
                w.z = f2bf(acc[ms][4 * g + 2] + bb);
                w.w = f2bf(acc[ms][4 * g + 3] + bb);
                *(ushort4*)&Ob[s] = w;
            }
    }
}

// ---------------------------------------------------------------------------
// attn (verbatim R1 attn_mfma body): one (qt,bh,sp) job per block,
// K/V LDS-staged (shared by 4 q-waves), VALU lsum, reg double-buffer,
// setprio around MFMA. XCD swizzle: 2 bh per XCD.
// ---------------------------------------------------------------------------
__device__ void attn_stage(Shm* shm, const KParams& P, int bid)
{
    const int tid = threadIdx.x;
    const int wid = tid >> 6;
    const int lane = tid & 63;
    const int l31 = lane & 31;
    const int hi = lane >> 5;

    const int swz = (bid & 7) * 64 + (bid >> 3);   // bijective, 512 blocks
    const int sp = swz & 3, qt = (swz >> 2) & 7, bh = swz >> 5;

    const short* Qg = P.Qbuf + (size_t)bh * SLEN * 64;
    const short* Kg = P.Kbuf + (size_t)bh * SLEN * 64;
    const short* Vg = P.Vtbuf + (size_t)bh * 64 * SLEN;

    const int q0 = qt * 256 + wid * 64;

    short8 qf[2][4];
#pragma unroll
    for (int nt = 0; nt < 2; ++nt)
#pragma unroll
        for (int ks = 0; ks < 4; ++ks)
            qf[nt][ks] = *(const short8*)&Qg[(size_t)(q0 + nt * 32 + l31) * 64 + ks * 16 + hi * 8];

    f32x16 oacc[2][2];
    float lsum[2] = {0.f, 0.f};
#pragma unroll
    for (int nt = 0; nt < 2; ++nt)
#pragma unroll
        for (int dt = 0; dt < 2; ++dt)
#pragma unroll
            for (int r = 0; r < 16; ++r) oacc[nt][dt][r] = 0.f;

    const int srow = tid >> 2;
    const int sch = (tid & 3) * 16;
    const int kbase = sp * (SLEN / SPLIT);
    short* Ks = shm->st.Ks;
    short* Vs = shm->st.Vs;

    // prologue: stage tile 0 into registers
    short8 rk0 = *(const short8*)&Kg[(size_t)(kbase + srow) * 64 + sch];
    short8 rk1 = *(const short8*)&Kg[(size_t)(kbase + srow) * 64 + sch + 8];
    short8 rv0 = *(const short8*)&Vg[(size_t)srow * SLEN + kbase + sch];
    short8 rv1 = *(const short8*)&Vg[(size_t)srow * SLEN + kbase + sch + 8];

#pragma unroll 1
    for (int kt = 0; kt < 8; ++kt) {
        __syncthreads();
        *(short8*)&Ks[srow * 72 + sch]     = rk0;
        *(short8*)&Ks[srow * 72 + sch + 8] = rk1;
        *(short8*)&Vs[srow * 72 + sch]     = rv0;
        *(short8*)&Vs[srow * 72 + sch + 8] = rv1;
        __syncthreads();

        if (kt < 7) {
            const int k0n = kbase + (kt + 1) * 64;
            rk0 = *(const short8*)&Kg[(size_t)(k0n + srow) * 64 + sch];
            rk1 = *(const short8*)&Kg[(size_t)(k0n + srow) * 64 + sch + 8];
            rv0 = *(const short8*)&Vg[(size_t)srow * SLEN + k0n + sch];
            rv1 = *(const short8*)&Vg[(size_t)srow * SLEN + k0n + sch + 8];
        }

        short8 kf[2][4], vf[2][4];
#pragma unroll
        for (int mt = 0; mt < 2; ++mt)
#pragma unroll
            for (int ks = 0; ks < 4; ++ks)
                kf[mt][ks] = *(const short8*)&Ks[(mt * 32 + l31) * 72 + ks * 16 + hi * 8];
#pragma unroll
        for (int dt = 0; dt < 2; ++dt)
#pragma unroll
            for (int p = 0; p < 4; ++p)
                vf[dt][p] = *(const short8*)&Vs[(dt * 32 + l31) * 72 + p * 16 + hi * 8];

#pragma unroll
        for (int nt = 0; nt < 2; ++nt) {
            f32x16 sacc[2];
            __builtin_amdgcn_s_setprio(1);
#pragma unroll
            for (int mt = 0; mt < 2; ++mt) {
                f32x16 s;
#pragma unroll
                for (int r = 0; r < 16; ++r) s[r] = 0.f;
#pragma unroll
                for (int ks = 0; ks < 4; ++ks)
                    s = __builtin_amdgcn_mfma_f32_32x32x16_bf16(kf[mt][ks], qf[nt][ks], s, 0, 0, 0);
                sacc[mt] = s;
            }
            __builtin_amdgcn_s_setprio(0);

            int2 pk[2][4];
#pragma unroll
            for (int mt = 0; mt < 2; ++mt)
#pragma unroll
                for (int g = 0; g < 4; ++g) {
                    unsigned a0 = __float_as_uint(__builtin_amdgcn_exp2f(sacc[mt][4 * g + 0]));
                    unsigned a1 = __float_as_uint(__builtin_amdgcn_exp2f(sacc[mt][4 * g + 1]));
                    unsigned a2 = __float_as_uint(__builtin_amdgcn_exp2f(sacc[mt][4 * g + 2]));
                    unsigned a3 = __float_as_uint(__builtin_amdgcn_exp2f(sacc[mt][4 * g + 3]));
                    float t0 = __uint_as_float(a0 & 0xffff0000u);
                    float t1 = __uint_as_float(a1 & 0xffff0000u);
                    float t2 = __uint_as_float(a2 & 0xffff0000u);
                    float t3 = __uint_as_float(a3 & 0xffff0000u);
                    lsum[nt] += (t0 + t1) + (t2 + t3);
                    pk[mt][g].x = (int)__builtin_amdgcn_perm(a1, a0, 0x07060302u);
                    pk[mt][g].y = (int)__builtin_amdgcn_perm(a3, a2, 0x07060302u);
                }

            int2 xch[2][2];
#pragma unroll
            for (int mt = 0; mt < 2; ++mt)
#pragma unroll
                for (int h2 = 0; h2 < 2; ++h2) {
                    int2 v = hi ? pk[mt][2 * h2] : pk[mt][2 * h2 + 1];
                    xch[mt][h2].x = __shfl_xor(v.x, 32);
                    xch[mt][h2].y = __shfl_xor(v.y, 32);
                }

            __builtin_amdgcn_s_setprio(1);
#pragma unroll
            for (int p = 0; p < 4; ++p) {
                const int mt = p >> 1, h2 = p & 1;
                const int ga = 2 * h2, gb = 2 * h2 + 1;
                const int2 X = xch[mt][h2];
                union { int4 i; short8 s; } u;
                u.i.x = hi ? X.x : pk[mt][ga].x;
                u.i.y = hi ? X.y : pk[mt][ga].y;
                u.i.z = hi ? pk[mt][gb].x : X.x;
                u.i.w = hi ? pk[mt][gb].y : X.y;
#pragma unroll
                for (int dt = 0; dt < 2; ++dt)
                    oacc[nt][dt] = __builtin_amdgcn_mfma_f32_32x32x16_bf16(u.s, vf[dt][p], oacc[nt][dt], 0, 0, 0);
            }
            __builtin_amdgcn_s_setprio(0);
        }
    }

#pragma unroll
    for (int nt = 0; nt < 2; ++nt) {
        float lt = lsum[nt] + __shfl_xor(lsum[nt], 32);
        if (hi == 0)
            P.lpart[((size_t)(sp * 16 + bh)) * SLEN + q0 + nt * 32 + l31] = lt;
#pragma unroll
        for (int dt = 0; dt < 2; ++dt) {
#pragma unroll
            for (int r = 0; r < 16; ++r) {
                int qrow = (r & 3) + 8 * (r >> 2) + 4 * hi;
                size_t addr = (((size_t)(sp * 16 + bh)) * SLEN + (q0 + nt * 32 + qrow)) * 64 + dt * 32 + l31;
                P.Opart[addr] = (short)f2bf(oacc[nt][dt][r]);
            }
        }
    }
}

// ---------------------------------------------------------------------------
// merge (verbatim R1 merge_k body, grid-strided)
// ---------------------------------------------------------------------------
__device__ void merge_stage(const KParams& P)
{
    for (int g = blockIdx.x * NTHR + threadIdx.x; g < 524288; g += NBLK * NTHR) {
        const int d4 = g & 15;
        const int s = (g >> 4) & (SLEN - 1);
        const int bh = g >> 15;

        float o[4] = {0.f, 0.f, 0.f, 0.f};
        float ls = 0.f;
#pragma unroll
        for (int sp = 0; sp < SPLIT; ++sp) {
            const size_t base = (((size_t)(sp * 16 + bh)) * SLEN + s);
            ushort4 u4 = *(const ushort4*)&P.Opart[base * 64 + d4 * 4];
            o[0] += bf2f((short)u4.x); o[1] += bf2f((short)u4.y);
            o[2] += bf2f((short)u4.z); o[3] += bf2f((short)u4.w);
            ls += P.lpart[base];
        }
        const int b = bh >> 3, h = bh & 7;
        const float inv = 1.f / ls;
        ushort4 w;
        w.x = f2bf(o[0] * inv); w.y = f2bf(o[1] * inv);
        w.z = f2bf(o[2] * inv); w.w = f2bf(o[3] * inv);
        *(ushort4*)&P.hcbf[((size_t)(b * SLEN + s)) * DDIM + h * 64 + d4 * 4] = w;
    }
}

// ---------------------------------------------------------------------------
// addnorm (verbatim R1 body, 8 rows per block)
// ---------------------------------------------------------------------------
__device__ void addnorm_rows(int bid, short* __restrict__ X,
    const float* __restrict__ Y, const float* __restrict__ g,
    const float* __restrict__ beta)
{
    const int lane = threadIdx.x & 63;
    const int c0 = lane * 8;

    float4 ga = *(const float4*)&g[c0];
    float4 gb = *(const float4*)&g[c0 + 4];
    float4 ba = *(const float4*)&beta[c0];
    float4 bb = *(const float4*)&beta[c0 + 4];
    float gg[8] = {ga.x, ga.y, ga.z, ga.w, gb.x, gb.y, gb.z, gb.w};
    float bt[8] = {ba.x, ba.y, ba.z, ba.w, bb.x, bb.y, bb.z, bb.w};

#pragma unroll
    for (int rr = 0; rr < 8; rr += 4) {
        const int t = bid * 8 + rr + (threadIdx.x >> 6);
        short* xr = X + (size_t)t * DDIM;
        const float* yr = Y + (size_t)t * DDIM;

        short8 x8 = *(const short8*)&xr[c0];
        float4 y0 = *(const float4*)&yr[c0];
        float4 y1 = *(const float4*)&yr[c0 + 4];
        float v[8];
        v[0] = bf2f(x8[0]) + y0.x; v[1] = bf2f(x8[1]) + y0.y;
        v[2] = bf2f(x8[2]) + y0.z; v[3] = bf2f(x8[3]) + y0.w;
        v[4] = bf2f(x8[4]) + y1.x; v[5] = bf2f(x8[5]) + y1.y;
        v[6] = bf2f(x8[6]) + y1.z; v[7] = bf2f(x8[7]) + y1.w;

        float s1 = 0.f, s2 = 0.f;
#pragma unroll
        for (int j = 0; j < 8; ++j) { s1 += v[j]; s2 += v[j] * v[j]; }
#pragma unroll
        for (int off = 1; off < 64; off <<= 1) {
            s1 += __shfl_xor(s1, off);
            s2 += __shfl_xor(s2, off);
        }
        float mean = s1 * (1.0f / DDIM);
        float var = s2 * (1.0f / DDIM) - mean * mean;
        float rstd = rsqrtf(var + 1e-5f);

        short8 o8;
#pragma unroll
        for (int j = 0; j < 8; ++j)
            o8[j] = (short)f2bf((v[j] - mean) * rstd * gg[j] + bt[j]);
        *(short8*)&xr[c0] = o8;
    }
}

// ---------------------------------------------------------------------------
// Persistent fused kernel: prep -> 2x(qkv, attn, merge, Wo, an1, W1, W2, an2)
// -> proj. 17 grid barriers replace 17 dispatch boundaries.
// ---------------------------------------------------------------------------
__global__ __launch_bounds__(NTHR, 2) void fused_k(KParams P)
{
    __shared__ Shm shm;
    const int bid = blockIdx.x;

    prep_stage(P);
    gridbar(P.bar);

    for (int i = 0; i < 2; ++i) {
        const size_t wOff = (size_t)i * 262144;

        // qkv: 768 jobs (24 ncol x 32 m-tiles of 128)
        {
            qkv_tile(&shm, P, bid % 24, (bid / 24) * 128, i);
            if (bid < 256) {
                int j2 = bid + 512;
                qkv_tile(&shm, P, j2 % 24, (j2 / 24) * 128, i);
            }
        }
        gridbar(P.bar);

        attn_stage(&shm, P, bid);
        gridbar(P.bar);

        merge_stage(P);
        gridbar(P.bar);

        gemm_tile(&shm, P.hcbf, P.Wot + wOff, P.bo + i * 512, P.y,
                  512, 512, 0, (bid >> 3) * 64, (bid & 7) * 64);
        gridbar(P.bar);

        addnorm_rows(bid, P.xbf, P.y, P.g1 + i * 512, P.be1 + i * 512);
        gridbar(P.bar);

        gemm_tile(&shm, P.xbf, P.W1t + wOff, P.b1 + i * 512, P.hidbf,
                  512, 512, 3, (bid >> 3) * 64, (bid & 7) * 64);
        gridbar(P.bar);

        gemm_tile(&shm, P.hidbf, P.W2t + wOff, P.b2 + i * 512, P.y,
                  512, 512, 0, (bid >> 3) * 64, (bid & 7) * 64);
        gridbar(P.bar);

        addnorm_rows(bid, P.xbf, P.y, P.g2 + i * 512, P.be2 + i * 512);
        gridbar(P.bar);
    }

    // final projection: 256 jobs (64 m x 4 n)
    if (bid < 256)
        gemm_tile(&shm, P.xbf, P.Wpt, P.bp, P.out,
                  256, 512, 0, (bid >> 2) * 64, (bid & 3) * 64);
}

// ---------------------------------------------------------------------------
// Workspace (MiB) — R1 layout, lifetime-checked:
//   [ 0, 4) xbf   [ 4, 8) Qbuf|hcbf  [ 8,12) Kbuf  [12,16) Vtbuf
//   [16,32) Opart | y fp32 [16,24) | hidbf [24,28)
//   [32,32.5) lpart   [33,39.25) weights bf16   [39.5,+64B) barrier
// ---------------------------------------------------------------------------
extern "C" void kernel_launch(void* const* d_in, const int* in_sizes, int n_in,
                              void* d_out, int out_size, void* d_ws, size_t ws_size,
                              hipStream_t stream)
{
    (void)in_sizes; (void)n_in; (void)out_size; (void)ws_size;
    char* wsb = (char*)d_ws;
    const size_t MB = 1024 * 1024;

    KParams P;
    P.x   = (const float*)d_in[0];
    P.Wq  = (const float*)d_in[1];
    P.bq  = (const float*)d_in[2];
    P.Wk  = (const float*)d_in[3];
    P.bk  = (const float*)d_in[4];
    P.Wv  = (const float*)d_in[5];
    P.bv  = (const float*)d_in[6];
    P.Wo  = (const float*)d_in[7];
    P.bo  = (const float*)d_in[8];
    P.g1  = (const float*)d_in[9];
    P.be1 = (const float*)d_in[10];
    P.W1  = (const float*)d_in[11];
    P.b1  = (const float*)d_in[12];
    P.W2  = (const float*)d_in[13];
    P.b2  = (const float*)d_in[14];
    P.g2  = (const float*)d_in[15];
    P.be2 = (const float*)d_in[16];
    P.Wp  = (const float*)d_in[17];
    P.bp  = (const float*)d_in[18];
    P.out = (float*)d_out;

    P.xbf   = (short*)(wsb + 0);
    P.Qbuf  = (short*)(wsb + 4 * MB);
    P.Kbuf  = (short*)(wsb + 8 * MB);
    P.Vtbuf = (short*)(wsb + 12 * MB);
    P.Opart = (short*)(wsb + 16 * MB);
    P.y     = (float*)(wsb + 16 * MB);   // overlay (disjoint lifetime)
    P.hidbf = (short*)(wsb + 24 * MB);   // overlay (disjoint lifetime)
    P.lpart = (float*)(wsb + 32 * MB);
    P.hcbf  = P.Qbuf;                     // overlay (Q dead after attn)
    P.Wqt   = (short*)(wsb + 33 * MB);
    P.Wkt   = (short*)(wsb + 34 * MB);
    P.Wvt   = (short*)(wsb + 35 * MB);
    P.Wot   = (short*)(wsb + 36 * MB);
    P.W1t   = (short*)(wsb + 37 * MB);
    P.W2t   = (short*)(wsb + 38 * MB);
    P.Wpt   = (short*)(wsb + 39 * MB);
    P.bar   = (unsigned*)(wsb + 39 * MB + 512 * 1024);

    hipMemsetAsync(P.bar, 0, 64, stream);
    fused_k<<<NBLK, NTHR, 0, stream>>>(P);
}

// Round 5
// 370.586 us; speedup vs baseline: 5.1541x; 5.1541x over previous
//
#include <hip/hip_runtime.h>
#include <hip/hip_bf16.h>

#define MDIM 4096      // B*S tokens
#define DDIM 512
#define HHEADS 8
#define SLEN 2048
#define TDIM 256
#define LDT 66
#define EXPC 0.1803368801111244f   // 0.125 * log2(e)

typedef __attribute__((ext_vector_type(8))) short short8;
typedef __attribute__((ext_vector_type(16))) float f32x16;

__device__ __forceinline__ unsigned short f2bf(float f) {
    union { __hip_bfloat16 h; unsigned short u; } c;
    c.h = __float2bfloat16(f);
    return c.u;
}
__device__ __forceinline__ float bf2f(short s) {
    return __uint_as_float((unsigned)(unsigned short)s << 16);
}

// ---------------------------------------------------------------------------
// prep v2: LDS-tiled 64x64 transposes -> coalesced float4 reads AND 16B
// bf16 stores (R0-R2 used scattered 2B stores). Blocks:
//   [0,384)   Wq/Wk/Wv  [L*H][512][64] -> [L*H][64][512]   (128 tiles each)
//   [384,768) Wo/W1/W2  [L][512][512]  -> [L][512][512]^T  (128 tiles each)
//   [768,800) Wp        [512][256]     -> [256][512]       (32 tiles)
//   [800,1056) x fp32 -> bf16 (grid-stride)
// ---------------------------------------------------------------------------
__global__ __launch_bounds__(256) void prep_k(
    const float* __restrict__ Wq, const float* __restrict__ Wk, const float* __restrict__ Wv,
    const float* __restrict__ Wo, const float* __restrict__ W1, const float* __restrict__ W2,
    const float* __restrict__ Wp, const float* __restrict__ x,
    short* __restrict__ Wqt, short* __restrict__ Wkt, short* __restrict__ Wvt,
    short* __restrict__ Wot, short* __restrict__ W1t, short* __restrict__ W2t,
    short* __restrict__ Wpt, short* __restrict__ xbf)
{
    __shared__ short T[64][72];
    const int b = blockIdx.x, tid = threadIdx.x;

    if (b >= 800) {
        const int idx = (b - 800) * 256 + tid;
        for (int e = idx; e < 262144; e += 65536) {
            float4 f0 = *(const float4*)&x[e * 8];
            float4 f1 = *(const float4*)&x[e * 8 + 4];
            short8 o;
            o[0] = (short)f2bf(f0.x); o[1] = (short)f2bf(f0.y);
            o[2] = (short)f2bf(f0.z); o[3] = (short)f2bf(f0.w);
            o[4] = (short)f2bf(f1.x); o[5] = (short)f2bf(f1.y);
            o[6] = (short)f2bf(f1.z); o[7] = (short)f2bf(f1.w);
            *(short8*)&xbf[e * 8] = o;
        }
        return;
    }

    const float* srcp; short* dstp; int ss;
    if (b < 384) {
        int w = b >> 7, t = b & 127;
        int lh = t >> 3, kt0 = (t & 7) << 6;
        const float* W = (w == 0) ? Wq : (w == 1) ? Wk : Wv;
        short* Wt = (w == 0) ? Wqt : (w == 1) ? Wkt : Wvt;
        srcp = W + (size_t)lh * 32768 + (size_t)kt0 * 64;
        dstp = Wt + (size_t)lh * 32768 + kt0;
        ss = 64;
    } else if (b < 768) {
        int w = (b - 384) >> 7, t = (b - 384) & 127;
        int l = t >> 6, tt = t & 63;
        int kt0 = (tt >> 3) << 6, nt0 = (tt & 7) << 6;
        const float* W = (w == 0) ? Wo : (w == 1) ? W1 : W2;
        short* Wt = (w == 0) ? Wot : (w == 1) ? W1t : W2t;
        srcp = W + (size_t)l * 262144 + (size_t)kt0 * 512 + nt0;
        dstp = Wt + (size_t)l * 262144 + (size_t)nt0 * 512 + kt0;
        ss = 512;
    } else {
        int t = b - 768;
        int kt0 = (t >> 2) << 6, nt0 = (t & 3) << 6;
        srcp = Wp + (size_t)kt0 * 256 + nt0;
        dstp = Wpt + (size_t)nt0 * 512 + kt0;
        ss = 256;
    }

    const int r = tid >> 2, c0 = (tid & 3) * 16;
#pragma unroll
    for (int j = 0; j < 16; j += 4) {
        float4 f = *(const float4*)&srcp[(size_t)r * ss + c0 + j];
        T[r][c0 + j + 0] = (short)f2bf(f.x);
        T[r][c0 + j + 1] = (short)f2bf(f.y);
        T[r][c0 + j + 2] = (short)f2bf(f.z);
        T[r][c0 + j + 3] = (short)f2bf(f.w);
    }
    __syncthreads();
    short8 o0, o1;
#pragma unroll
    for (int j = 0; j < 8; ++j) { o0[j] = T[c0 + j][r]; o1[j] = T[c0 + 8 + j][r]; }
    *(short8*)&dstp[(size_t)r * 512 + c0] = o0;
    *(short8*)&dstp[(size_t)r * 512 + c0 + 8] = o1;
}

// ---------------------------------------------------------------------------
// bf16 MFMA GEMM, 128m x 64n tile (qkv-proven structure), BK=64, 4 waves
// (2wm x 2wn), each wave 2 m-subtiles of 32x32. B transposed Bt[n][k].
// flags: 1=relu, 2=bf16 out.
// ---------------------------------------------------------------------------
__global__ __launch_bounds__(256, 2) void gemm_bf(
    const short* __restrict__ A, const short* __restrict__ Bt,
    const float* __restrict__ bias, void* __restrict__ Cout,
    int N, int K, int flags)
{
    __shared__ short As[128 * LDT];
    __shared__ short Bs[64 * LDT];
    const int tid = threadIdx.x;
    const int wave = tid >> 6, lane = tid & 63;
    const int l31 = lane & 31, hi = lane >> 5;
    const int wm = wave >> 1, wn = wave & 1;
    const int m0 = blockIdx.y * 128, n0 = blockIdx.x * 64;

    f32x16 acc[2];
#pragma unroll
    for (int ms = 0; ms < 2; ++ms)
#pragma unroll
        for (int r = 0; r < 16; ++r) acc[ms][r] = 0.f;

    const int sr = tid >> 3;
    const int sc = (tid & 7) * 8;

    for (int k0 = 0; k0 < K; k0 += 64) {
        __syncthreads();
#pragma unroll
        for (int p = 0; p < 4; ++p)
            *(short8*)&As[(p * 32 + sr) * LDT + sc] =
                *(const short8*)&A[(size_t)(m0 + p * 32 + sr) * K + k0 + sc];
#pragma unroll
        for (int p = 0; p < 2; ++p)
            *(short8*)&Bs[(p * 32 + sr) * LDT + sc] =
                *(const short8*)&Bt[(size_t)(n0 + p * 32 + sr) * K + k0 + sc];
        __syncthreads();

        short8 af[2][4], bfm[4];
#pragma unroll
        for (int ms = 0; ms < 2; ++ms)
#pragma unroll
            for (int ks = 0; ks < 4; ++ks)
                af[ms][ks] = *(const short8*)&As[(wm * 64 + ms * 32 + l31) * LDT + ks * 16 + hi * 8];
#pragma unroll
        for (int ks = 0; ks < 4; ++ks)
            bfm[ks] = *(const short8*)&Bs[(wn * 32 + l31) * LDT + ks * 16 + hi * 8];
#pragma unroll
        for (int ms = 0; ms < 2; ++ms)
#pragma unroll
            for (int ks = 0; ks < 4; ++ks)
                acc[ms] = __builtin_amdgcn_mfma_f32_32x32x16_bf16(af[ms][ks], bfm[ks], acc[ms], 0, 0, 0);
    }

    const int col = n0 + wn * 32 + l31;
    const float bb = bias[col];
#pragma unroll
    for (int ms = 0; ms < 2; ++ms) {
        const int rbase = m0 + wm * 64 + ms * 32 + 4 * hi;
#pragma unroll
        for (int r = 0; r < 16; ++r) {
            int row = rbase + (r & 3) + 8 * (r >> 2);
            float v = acc[ms][r] + bb;
            if (flags & 1) v = fmaxf(v, 0.f);
            if (flags & 2) ((short*)Cout)[(size_t)row * N + col] = (short)f2bf(v);
            else           ((float*)Cout)[(size_t)row * N + col] = v;
        }
    }
}

// ---------------------------------------------------------------------------
// Fused QKV MFMA GEMM (verbatim R1): A=xbf [4096,512]; grid (24, 32).
// Q pre-scaled by 0.125*log2(e); Q,K [bh][s][64] bf16; V transposed [bh][d][s].
// ---------------------------------------------------------------------------
__global__ __launch_bounds__(256, 2) void qkv_bf(
    const short* __restrict__ A,
    const short* __restrict__ Wqt, const short* __restrict__ Wkt, const short* __restrict__ Wvt,
    const float* __restrict__ bq, const float* __restrict__ bk, const float* __restrict__ bv,
    short* __restrict__ Oq, short* __restrict__ Ok, short* __restrict__ Ov)
{
    __shared__ short As[128 * LDT];
    __shared__ short Bs[64 * LDT];
    const int tid = threadIdx.x;
    const int wave = tid >> 6, lane = tid & 63;
    const int l31 = lane & 31, hi = lane >> 5;
    const int wm = wave >> 1, wn = wave & 1;
    const int m0 = blockIdx.y * 128;
    const int nt = blockIdx.x;
    const int which = nt >> 3, h = nt & 7;

    const short* Bt = ((which == 0) ? Wqt : (which == 1) ? Wkt : Wvt) + (size_t)h * 64 * 512;
    const float* bias = ((which == 0) ? bq : (which == 1) ? bk : bv) + h * 64;
    short* Out = (which == 0) ? Oq : (which == 1) ? Ok : Ov;

    f32x16 acc[2];
#pragma unroll
    for (int ms = 0; ms < 2; ++ms)
#pragma unroll
        for (int r = 0; r < 16; ++r) acc[ms][r] = 0.f;

    const int sr = tid >> 3;
    const int sc = (tid & 7) * 8;

    for (int k0 = 0; k0 < 512; k0 += 64) {
        __syncthreads();
#pragma unroll
        for (int p = 0; p < 4; ++p)
            *(short8*)&As[(p * 32 + sr) * LDT + sc] =
                *(const short8*)&A[(size_t)(m0 + p * 32 + sr) * 512 + k0 + sc];
#pragma unroll
        for (int p = 0; p < 2; ++p)
            *(short8*)&Bs[(p * 32 + sr) * LDT + sc] =
                *(const short8*)&Bt[(size_t)(p * 32 + sr) * 512 + k0 + sc];
        __syncthreads();

        short8 af[2][4], bfm[4];
#pragma unroll
        for (int ms = 0; ms < 2; ++ms)
#pragma unroll
            for (int ks = 0; ks < 4; ++ks)
                af[ms][ks] = *(const short8*)&As[(wm * 64 + ms * 32 + l31) * LDT + ks * 16 + hi * 8];
#pragma unroll
        for (int ks = 0; ks < 4; ++ks)
            bfm[ks] = *(const short8*)&Bs[(wn * 32 + l31) * LDT + ks * 16 + hi * 8];
#pragma unroll
        for (int ms = 0; ms < 2; ++ms)
#pragma unroll
            for (int ks = 0; ks < 4; ++ks)
                acc[ms] = __builtin_amdgcn_mfma_f32_32x32x16_bf16(af[ms][ks], bfm[ks], acc[ms], 0, 0, 0);
    }

    const int a = wn * 32 + l31;
    const float bb = bias[a];
    const int b = m0 >> 11;
    const int sb = (m0 & (SLEN - 1)) + wm * 64;
    const int bh = b * HHEADS + h;

    if (which == 0) {
        short* Ob = Out + (size_t)bh * SLEN * 64;
#pragma unroll
        for (int ms = 0; ms < 2; ++ms)
#pragma unroll
            for (int r = 0; r < 16; ++r) {
                int s = sb + ms * 32 + (r & 3) + 8 * (r >> 2) + 4 * hi;
                Ob[(size_t)s * 64 + a] = (short)f2bf((acc[ms][r] + bb) * EXPC);
            }
    } else if (which == 1) {
        short* Ob = Out + (size_t)bh * SLEN * 64;
#pragma unroll
        for (int ms = 0; ms < 2; ++ms)
#pragma unroll
            for (int r = 0; r < 16; ++r) {
                int s = sb + ms * 32 + (r & 3) + 8 * (r >> 2) + 4 * hi;
                Ob[(size_t)s * 64 + a] = (short)f2bf(acc[ms][r] + bb);
            }
    } else {
        short* Ob = Out + ((size_t)bh * 64 + a) * SLEN;
#pragma unroll
        for (int ms = 0; ms < 2; ++ms)
#pragma unroll
            for (int g = 0; g < 4; ++g) {
                int s = sb + ms * 32 + 8 * g + 4 * hi;
                ushort4 w;
                w.x = f2bf(acc[ms][4 * g + 0] + bb);
                w.y = f2bf(acc[ms][4 * g + 1] + bb);
                w.z = f2bf(acc[ms][4 * g + 2] + bb);
                w.w = f2bf(acc[ms][4 * g + 3] + bb);
                *(ushort4*)&Ob[s] = w;
            }
    }
}

// ---------------------------------------------------------------------------
// attn v3: NO key-split. grid 256 = (qt 16 x bh 16), 4 waves x 32 q-rows,
// full 2048-key sweep (32 LDS tiles shared by the 4 waves, reg-dbuf).
// l + O finalized in-wave (fp32 accumulation end-to-end, 16 shfl broadcasts
// of 1/l), normalized bf16 written DIRECTLY to hc. Opart/lpart/merge gone.
// XCD swizzle: 2 bh per XCD (K/V 1 MB L2-resident).
// ---------------------------------------------------------------------------
__global__ __launch_bounds__(256, 2) void attn_mfma(
    const short* __restrict__ Qb, const short* __restrict__ Kb,
    const short* __restrict__ Vtb, short* __restrict__ hc)
{
    __shared__ short Ks[64 * 72];
    __shared__ short Vs[64 * 72];

    const int tid = threadIdx.x;
    const int wid = tid >> 6;
    const int lane = tid & 63;
    const int l31 = lane & 31;
    const int hi = lane >> 5;

    const int bidx = blockIdx.x;                 // 256 blocks
    const int swz = (bidx & 7) * 32 + (bidx >> 3);
    const int qt = swz & 15, bh = swz >> 4;

    const short* Qg = Qb + (size_t)bh * SLEN * 64;
    const short* Kg = Kb + (size_t)bh * SLEN * 64;
    const short* Vg = Vtb + (size_t)bh * 64 * SLEN;

    const int q0 = qt * 128 + wid * 32;

    short8 qf[4];
#pragma unroll
    for (int ks = 0; ks < 4; ++ks)
        qf[ks] = *(const short8*)&Qg[(size_t)(q0 + l31) * 64 + ks * 16 + hi * 8];

    f32x16 oacc[2];
    float lsum = 0.f;
#pragma unroll
    for (int dt = 0; dt < 2; ++dt)
#pragma unroll
        for (int r = 0; r < 16; ++r) oacc[dt][r] = 0.f;

    const int srow = tid >> 2;
    const int sch = (tid & 3) * 16;

    // prologue: stage tile 0 into registers
    short8 rk0 = *(const short8*)&Kg[(size_t)srow * 64 + sch];
    short8 rk1 = *(const short8*)&Kg[(size_t)srow * 64 + sch + 8];
    short8 rv0 = *(const short8*)&Vg[(size_t)srow * SLEN + sch];
    short8 rv1 = *(const short8*)&Vg[(size_t)srow * SLEN + sch + 8];

#pragma unroll 1
    for (int kt = 0; kt < 32; ++kt) {
        __syncthreads();
        *(short8*)&Ks[srow * 72 + sch]     = rk0;
        *(short8*)&Ks[srow * 72 + sch + 8] = rk1;
        *(short8*)&Vs[srow * 72 + sch]     = rv0;
        *(short8*)&Vs[srow * 72 + sch + 8] = rv1;
        __syncthreads();

        if (kt < 31) {
            const int k0n = (kt + 1) * 64;
            rk0 = *(const short8*)&Kg[(size_t)(k0n + srow) * 64 + sch];
            rk1 = *(const short8*)&Kg[(size_t)(k0n + srow) * 64 + sch + 8];
            rv0 = *(const short8*)&Vg[(size_t)srow * SLEN + k0n + sch];
            rv1 = *(const short8*)&Vg[(size_t)srow * SLEN + k0n + sch + 8];
        }

        short8 kf[2][4], vf[2][4];
#pragma unroll
        for (int mt = 0; mt < 2; ++mt)
#pragma unroll
            for (int ks = 0; ks < 4; ++ks)
                kf[mt][ks] = *(const short8*)&Ks[(mt * 32 + l31) * 72 + ks * 16 + hi * 8];
#pragma unroll
        for (int dt = 0; dt < 2; ++dt)
#pragma unroll
            for (int p = 0; p < 4; ++p)
                vf[dt][p] = *(const short8*)&Vs[(dt * 32 + l31) * 72 + p * 16 + hi * 8];

        f32x16 sacc[2];
        __builtin_amdgcn_s_setprio(1);
#pragma unroll
        for (int mt = 0; mt < 2; ++mt) {
            f32x16 s;
#pragma unroll
            for (int r = 0; r < 16; ++r) s[r] = 0.f;
#pragma unroll
            for (int ks = 0; ks < 4; ++ks)
                s = __builtin_amdgcn_mfma_f32_32x32x16_bf16(kf[mt][ks], qf[ks], s, 0, 0, 0);
            sacc[mt] = s;
        }
        __builtin_amdgcn_s_setprio(0);

        // p = exp2(s); pack via v_perm truncation; VALU lsum on the SAME
        // truncated values (numerator/denominator rounding matched).
        int2 pk[2][4];
#pragma unroll
        for (int mt = 0; mt < 2; ++mt)
#pragma unroll
            for (int g = 0; g < 4; ++g) {
                unsigned a0 = __float_as_uint(__builtin_amdgcn_exp2f(sacc[mt][4 * g + 0]));
                unsigned a1 = __float_as_uint(__builtin_amdgcn_exp2f(sacc[mt][4 * g + 1]));
                unsigned a2 = __float_as_uint(__builtin_amdgcn_exp2f(sacc[mt][4 * g + 2]));
                unsigned a3 = __float_as_uint(__builtin_amdgcn_exp2f(sacc[mt][4 * g + 3]));
                float t0 = __uint_as_float(a0 & 0xffff0000u);
                float t1 = __uint_as_float(a1 & 0xffff0000u);
                float t2 = __uint_as_float(a2 & 0xffff0000u);
                float t3 = __uint_as_float(a3 & 0xffff0000u);
                lsum += (t0 + t1) + (t2 + t3);
                pk[mt][g].x = (int)__builtin_amdgcn_perm(a1, a0, 0x07060302u);
                pk[mt][g].y = (int)__builtin_amdgcn_perm(a3, a2, 0x07060302u);
            }

        // minimal cross-half exchange: partner needs pk[2h2 + (1-hi)]
        int2 xch[2][2];
#pragma unroll
        for (int mt = 0; mt < 2; ++mt)
#pragma unroll
            for (int h2 = 0; h2 < 2; ++h2) {
                int2 v = hi ? pk[mt][2 * h2] : pk[mt][2 * h2 + 1];
                xch[mt][h2].x = __shfl_xor(v.x, 32);
                xch[mt][h2].y = __shfl_xor(v.y, 32);
            }

        __builtin_amdgcn_s_setprio(1);
#pragma unroll
        for (int p = 0; p < 4; ++p) {
            const int mt = p >> 1, h2 = p & 1;
            const int ga = 2 * h2, gb = 2 * h2 + 1;
            const int2 X = xch[mt][h2];
            union { int4 i; short8 s; } u;
            u.i.x = hi ? X.x : pk[mt][ga].x;
            u.i.y = hi ? X.y : pk[mt][ga].y;
            u.i.z = hi ? pk[mt][gb].x : X.x;
            u.i.w = hi ? pk[mt][gb].y : X.y;
#pragma unroll
            for (int dt = 0; dt < 2; ++dt)
                oacc[dt] = __builtin_amdgcn_mfma_f32_32x32x16_bf16(u.s, vf[dt][p], oacc[dt], 0, 0, 0);
        }
        __builtin_amdgcn_s_setprio(0);
    }

    // ---- in-wave finalize: l broadcast + normalized direct hc write ----
    const float lt = lsum + __shfl_xor(lsum, 32);   // lanes q,q+32 hold l[q0+q]
    const float invl = 1.f / lt;
    const int b = bh >> 3, h = bh & 7;
#pragma unroll
    for (int r = 0; r < 16; ++r) {
        const int qrow = (r & 3) + 8 * (r >> 2) + 4 * hi;
        const float iv = __shfl(invl, qrow);        // 1/l for row q0+qrow
        const size_t rowb = ((size_t)(b * SLEN + q0 + qrow)) * DDIM + h * 64;
#pragma unroll
        for (int dt = 0; dt < 2; ++dt)
            hc[rowb + dt * 32 + l31] = (short)f2bf(oacc[dt][r] * iv);
    }
}

// ---------------------------------------------------------------------------
// AddNorm on bf16 stream (verbatim R1): xbf = LN(xbf + y) * g + b ; y fp32.
// ---------------------------------------------------------------------------
__global__ __launch_bounds__(256) void addnorm_bf(
    short* __restrict__ X, const float* __restrict__ Y,
    const float* __restrict__ g, const float* __restrict__ beta)
{
    const int lane = threadIdx.x & 63;
    const int t = blockIdx.x * 4 + (threadIdx.x >> 6);
    short* xr = X + (size_t)t * DDIM;
    const float* yr = Y + (size_t)t * DDIM;
    const int c0 = lane * 8;

    short8 x8 = *(const short8*)&xr[c0];
    float4 y0 = *(const float4*)&yr[c0];
    float4 y1 = *(const float4*)&yr[c0 + 4];
    float v[8];
    v[0] = bf2f(x8[0]) + y0.x; v[1] = bf2f(x8[1]) + y0.y;
    v[2] = bf2f(x8[2]) + y0.z; v[3] = bf2f(x8[3]) + y0.w;
    v[4] = bf2f(x8[4]) + y1.x; v[5] = bf2f(x8[5]) + y1.y;
    v[6] = bf2f(x8[6]) + y1.z; v[7] = bf2f(x8[7]) + y1.w;

    float s1 = 0.f, s2 = 0.f;
#pragma unroll
    for (int j = 0; j < 8; ++j) { s1 += v[j]; s2 += v[j] * v[j]; }
#pragma unroll
    for (int off = 1; off < 64; off <<= 1) {
        s1 += __shfl_xor(s1, off);
        s2 += __shfl_xor(s2, off);
    }
    float mean = s1 * (1.0f / DDIM);
    float var = s2 * (1.0f / DDIM) - mean * mean;
    float rstd = rsqrtf(var + 1e-5f);

    float4 ga = *(const float4*)&g[c0];
    float4 gb = *(const float4*)&g[c0 + 4];
    float4 ba = *(const float4*)&beta[c0];
    float4 bb = *(const float4*)&beta[c0 + 4];
    float gg[8] = {ga.x, ga.y, ga.z, ga.w, gb.x, gb.y, gb.z, gb.w};
    float bt[8] = {ba.x, ba.y, ba.z, ba.w, bb.x, bb.y, bb.z, bb.w};

    short8 o8;
#pragma unroll
    for (int j = 0; j < 8; ++j)
        o8[j] = (short)f2bf((v[j] - mean) * rstd * gg[j] + bt[j]);
    *(short8*)&xr[c0] = o8;
}

// ---------------------------------------------------------------------------
// Workspace (MiB), lifetime-checked, < 40 MiB:
//   [ 0, 4) xbf   [ 4, 8) Qbuf   [ 8,12) Kbuf   [12,16) Vtbuf
//   [16,20) hcbf (separate: attn reads Q while writing hc)
//   [20,28) y fp32   [28,32) hidbf   [33,39.25) weights bf16
// ---------------------------------------------------------------------------
extern "C" void kernel_launch(void* const* d_in, const int* in_sizes, int n_in,
                              void* d_out, int out_size, void* d_ws, size_t ws_size,
                              hipStream_t stream)
{
    (void)in_sizes; (void)n_in; (void)out_size; (void)ws_size;
    const float* x   = (const float*)d_in[0];
    const float* Wq  = (const float*)d_in[1];
    const float* bq  = (const float*)d_in[2];
    const float* Wk  = (const float*)d_in[3];
    const float* bk  = (const float*)d_in[4];
    const float* Wv  = (const float*)d_in[5];
    const float* bv  = (const float*)d_in[6];
    const float* Wo  = (const float*)d_in[7];
    const float* bo  = (const float*)d_in[8];
    const float* g1  = (const float*)d_in[9];
    const float* be1 = (const float*)d_in[10];
    const float* W1  = (const float*)d_in[11];
    const float* b1  = (const float*)d_in[12];
    const float* W2  = (const float*)d_in[13];
    const float* b2  = (const float*)d_in[14];
    const float* g2  = (const float*)d_in[15];
    const float* be2 = (const float*)d_in[16];
    const float* Wp  = (const float*)d_in[17];
    const float* bp  = (const float*)d_in[18];

    char* wsb = (char*)d_ws;
    const size_t MB = 1024 * 1024;
    short* xbf   = (short*)(wsb + 0);
    short* Qbuf  = (short*)(wsb + 4 * MB);
    short* Kbuf  = (short*)(wsb + 8 * MB);
    short* Vtbuf = (short*)(wsb + 12 * MB);
    short* hcbf  = (short*)(wsb + 16 * MB);
    float* y     = (float*)(wsb + 20 * MB);
    short* hidbf = (short*)(wsb + 28 * MB);
    short* Wqt   = (short*)(wsb + 33 * MB);
    short* Wkt   = (short*)(wsb + 34 * MB);
    short* Wvt   = (short*)(wsb + 35 * MB);
    short* Wot   = (short*)(wsb + 36 * MB);
    short* W1t   = (short*)(wsb + 37 * MB);
    short* W2t   = (short*)(wsb + 38 * MB);
    short* Wpt   = (short*)(wsb + 39 * MB);

    prep_k<<<1056, 256, 0, stream>>>(Wq, Wk, Wv, Wo, W1, W2, Wp, x,
                                     Wqt, Wkt, Wvt, Wot, W1t, W2t, Wpt, xbf);

    for (int i = 0; i < 2; ++i) {
        const size_t wOff = (size_t)i * 262144;
        qkv_bf<<<dim3(24, 32), 256, 0, stream>>>(
            xbf, Wqt + wOff, Wkt + wOff, Wvt + wOff,
            bq + i * 512, bk + i * 512, bv + i * 512,
            Qbuf, Kbuf, Vtbuf);
        attn_mfma<<<256, 256, 0, stream>>>(Qbuf, Kbuf, Vtbuf, hcbf);
        gemm_bf<<<dim3(8, 32), 256, 0, stream>>>(
            hcbf, Wot + wOff, bo + i * 512, y, 512, 512, 0);
        addnorm_bf<<<1024, 256, 0, stream>>>(xbf, y, g1 + i * 512, be1 + i * 512);
        gemm_bf<<<dim3(8, 32), 256, 0, stream>>>(
            xbf, W1t + wOff, b1 + i * 512, hidbf, 512, 512, 3);
        gemm_bf<<<dim3(8, 32), 256, 0, stream>>>(
            hidbf, W2t + wOff, b2 + i * 512, y, 512, 512, 0);
        addnorm_bf<<<1024, 256, 0, stream>>>(xbf, y, g2 + i * 512, be2 + i * 512);
    }
    gemm_bf<<<dim3(4, 32), 256, 0, stream>>>(
        xbf, Wpt, bp, (float*)d_out, 256, 512, 0);
}

// Round 6
// 327.290 us; speedup vs baseline: 5.8359x; 1.1323x over previous
//
#include <hip/hip_runtime.h>
#include <hip/hip_bf16.h>

#define MDIM 4096      // B*S tokens
#define DDIM 512
#define HHEADS 8
#define SLEN 2048
#define TDIM 256
#define LDT 66
#define EXPC 0.1803368801111244f   // 0.125 * log2(e)

typedef __attribute__((ext_vector_type(8))) short short8;
typedef __attribute__((ext_vector_type(16))) float f32x16;

__device__ __forceinline__ unsigned short f2bf(float f) {
    union { __hip_bfloat16 h; unsigned short u; } c;
    c.h = __float2bfloat16(f);
    return c.u;
}
__device__ __forceinline__ float bf2f(short s) {
    return __uint_as_float((unsigned)(unsigned short)s << 16);
}

// ---------------------------------------------------------------------------
// prep (R5 version, coalesced both ways): LDS-tiled 64x64 transposes.
//   [0,384)   Wq/Wk/Wv  [L*H][512][64] -> [L*H][64][512]
//   [384,768) Wo/W1/W2  [L][512][512]  -> [L][512][512]^T
//   [768,800) Wp        [512][256]     -> [256][512]
//   [800,1056) x fp32 -> bf16
// ---------------------------------------------------------------------------
__global__ __launch_bounds__(256) void prep_k(
    const float* __restrict__ Wq, const float* __restrict__ Wk, const float* __restrict__ Wv,
    const float* __restrict__ Wo, const float* __restrict__ W1, const float* __restrict__ W2,
    const float* __restrict__ Wp, const float* __restrict__ x,
    short* __restrict__ Wqt, short* __restrict__ Wkt, short* __restrict__ Wvt,
    short* __restrict__ Wot, short* __restrict__ W1t, short* __restrict__ W2t,
    short* __restrict__ Wpt, short* __restrict__ xbf)
{
    __shared__ short T[64][72];
    const int b = blockIdx.x, tid = threadIdx.x;

    if (b >= 800) {
        const int idx = (b - 800) * 256 + tid;
        for (int e = idx; e < 262144; e += 65536) {
            float4 f0 = *(const float4*)&x[e * 8];
            float4 f1 = *(const float4*)&x[e * 8 + 4];
            short8 o;
            o[0] = (short)f2bf(f0.x); o[1] = (short)f2bf(f0.y);
            o[2] = (short)f2bf(f0.z); o[3] = (short)f2bf(f0.w);
            o[4] = (short)f2bf(f1.x); o[5] = (short)f2bf(f1.y);
            o[6] = (short)f2bf(f1.z); o[7] = (short)f2bf(f1.w);
            *(short8*)&xbf[e * 8] = o;
        }
        return;
    }

    const float* srcp; short* dstp; int ss;
    if (b < 384) {
        int w = b >> 7, t = b & 127;
        int lh = t >> 3, kt0 = (t & 7) << 6;
        const float* W = (w == 0) ? Wq : (w == 1) ? Wk : Wv;
        short* Wt = (w == 0) ? Wqt : (w == 1) ? Wkt : Wvt;
        srcp = W + (size_t)lh * 32768 + (size_t)kt0 * 64;
        dstp = Wt + (size_t)lh * 32768 + kt0;
        ss = 64;
    } else if (b < 768) {
        int w = (b - 384) >> 7, t = (b - 384) & 127;
        int l = t >> 6, tt = t & 63;
        int kt0 = (tt >> 3) << 6, nt0 = (tt & 7) << 6;
        const float* W = (w == 0) ? Wo : (w == 1) ? W1 : W2;
        short* Wt = (w == 0) ? Wot : (w == 1) ? W1t : W2t;
        srcp = W + (size_t)l * 262144 + (size_t)kt0 * 512 + nt0;
        dstp = Wt + (size_t)l * 262144 + (size_t)nt0 * 512 + kt0;
        ss = 512;
    } else {
        int t = b - 768;
        int kt0 = (t >> 2) << 6, nt0 = (t & 3) << 6;
        srcp = Wp + (size_t)kt0 * 256 + nt0;
        dstp = Wpt + (size_t)nt0 * 512 + kt0;
        ss = 256;
    }

    const int r = tid >> 2, c0 = (tid & 3) * 16;
#pragma unroll
    for (int j = 0; j < 16; j += 4) {
        float4 f = *(const float4*)&srcp[(size_t)r * ss + c0 + j];
        T[r][c0 + j + 0] = (short)f2bf(f.x);
        T[r][c0 + j + 1] = (short)f2bf(f.y);
        T[r][c0 + j + 2] = (short)f2bf(f.z);
        T[r][c0 + j + 3] = (short)f2bf(f.w);
    }
    __syncthreads();
    short8 o0, o1;
#pragma unroll
    for (int j = 0; j < 8; ++j) { o0[j] = T[c0 + j][r]; o1[j] = T[c0 + 8 + j][r]; }
    *(short8*)&dstp[(size_t)r * 512 + c0] = o0;
    *(short8*)&dstp[(size_t)r * 512 + c0 + 8] = o1;
}

// ---------------------------------------------------------------------------
// bf16 MFMA GEMM (verbatim R0, proven): C[M,N] = A[M,K] @ B + bias.
// Bt[n][k]. Tile 64m x 64n, BK=64, 4 waves (2m x 2n). Grids >= 512 blocks.
// flags: 1=relu, 2=bf16 out.
// ---------------------------------------------------------------------------
__global__ __launch_bounds__(256, 2) void gemm_bf(
    const short* __restrict__ A, const short* __restrict__ Bt,
    const float* __restrict__ bias, void* __restrict__ Cout,
    int M, int N, int K, int flags)
{
    __shared__ short As[64 * LDT];
    __shared__ short Bs[64 * LDT];
    const int tid = threadIdx.x;
    const int wave = tid >> 6, lane = tid & 63;
    const int l31 = lane & 31, hi = lane >> 5;
    const int wm = wave >> 1, wn = wave & 1;
    const int m0 = blockIdx.y * 64, n0 = blockIdx.x * 64;

    f32x16 acc;
#pragma unroll
    for (int r = 0; r < 16; ++r) acc[r] = 0.f;

    const int sr = tid >> 2;          // 0..63
    const int sc = (tid & 3) * 16;    // short chunk

    for (int k0 = 0; k0 < K; k0 += 64) {
        __syncthreads();
        *(short8*)&As[sr * LDT + sc]     = *(const short8*)&A[(size_t)(m0 + sr) * K + k0 + sc];
        *(short8*)&As[sr * LDT + sc + 8] = *(const short8*)&A[(size_t)(m0 + sr) * K + k0 + sc + 8];
        *(short8*)&Bs[sr * LDT + sc]     = *(const short8*)&Bt[(size_t)(n0 + sr) * K + k0 + sc];
        *(short8*)&Bs[sr * LDT + sc + 8] = *(const short8*)&Bt[(size_t)(n0 + sr) * K + k0 + sc + 8];
        __syncthreads();

        short8 af[4], bfm[4];
#pragma unroll
        for (int ks = 0; ks < 4; ++ks) {
            af[ks]  = *(const short8*)&As[(wm * 32 + l31) * LDT + ks * 16 + hi * 8];
            bfm[ks] = *(const short8*)&Bs[(wn * 32 + l31) * LDT + ks * 16 + hi * 8];
        }
#pragma unroll
        for (int ks = 0; ks < 4; ++ks)
            acc = __builtin_amdgcn_mfma_f32_32x32x16_bf16(af[ks], bfm[ks], acc, 0, 0, 0);
    }

    const int col = n0 + wn * 32 + l31;
    const float bb = bias[col];
    const int rbase = m0 + wm * 32 + 4 * hi;
#pragma unroll
    for (int r = 0; r < 16; ++r) {
        int row = rbase + (r & 3) + 8 * (r >> 2);
        float v = acc[r] + bb;
        if (flags & 1) v = fmaxf(v, 0.f);
        if (flags & 2) ((short*)Cout)[(size_t)row * N + col] = (short)f2bf(v);
        else           ((float*)Cout)[(size_t)row * N + col] = v;
    }
}

// ---------------------------------------------------------------------------
// Fused QKV MFMA GEMM (verbatim R1): A=xbf [4096,512]; grid (24, 32).
// Q pre-scaled by 0.125*log2(e); Q,K [bh][s][64] bf16; V transposed [bh][d][s].
// ---------------------------------------------------------------------------
__global__ __launch_bounds__(256, 2) void qkv_bf(
    const short* __restrict__ A,
    const short* __restrict__ Wqt, const short* __restrict__ Wkt, const short* __restrict__ Wvt,
    const float* __restrict__ bq, const float* __restrict__ bk, const float* __restrict__ bv,
    short* __restrict__ Oq, short* __restrict__ Ok, short* __restrict__ Ov)
{
    __shared__ short As[128 * LDT];
    __shared__ short Bs[64 * LDT];
    const int tid = threadIdx.x;
    const int wave = tid >> 6, lane = tid & 63;
    const int l31 = lane & 31, hi = lane >> 5;
    const int wm = wave >> 1, wn = wave & 1;
    const int m0 = blockIdx.y * 128;
    const int nt = blockIdx.x;
    const int which = nt >> 3, h = nt & 7;

    const short* Bt = ((which == 0) ? Wqt : (which == 1) ? Wkt : Wvt) + (size_t)h * 64 * 512;
    const float* bias = ((which == 0) ? bq : (which == 1) ? bk : bv) + h * 64;
    short* Out = (which == 0) ? Oq : (which == 1) ? Ok : Ov;

    f32x16 acc[2];
#pragma unroll
    for (int ms = 0; ms < 2; ++ms)
#pragma unroll
        for (int r = 0; r < 16; ++r) acc[ms][r] = 0.f;

    const int sr = tid >> 3;
    const int sc = (tid & 7) * 8;

    for (int k0 = 0; k0 < 512; k0 += 64) {
        __syncthreads();
#pragma unroll
        for (int p = 0; p < 4; ++p)
            *(short8*)&As[(p * 32 + sr) * LDT + sc] =
                *(const short8*)&A[(size_t)(m0 + p * 32 + sr) * 512 + k0 + sc];
#pragma unroll
        for (int p = 0; p < 2; ++p)
            *(short8*)&Bs[(p * 32 + sr) * LDT + sc] =
                *(const short8*)&Bt[(size_t)(p * 32 + sr) * 512 + k0 + sc];
        __syncthreads();

        short8 af[2][4], bfm[4];
#pragma unroll
        for (int ms = 0; ms < 2; ++ms)
#pragma unroll
            for (int ks = 0; ks < 4; ++ks)
                af[ms][ks] = *(const short8*)&As[(wm * 64 + ms * 32 + l31) * LDT + ks * 16 + hi * 8];
#pragma unroll
        for (int ks = 0; ks < 4; ++ks)
            bfm[ks] = *(const short8*)&Bs[(wn * 32 + l31) * LDT + ks * 16 + hi * 8];
#pragma unroll
        for (int ms = 0; ms < 2; ++ms)
#pragma unroll
            for (int ks = 0; ks < 4; ++ks)
                acc[ms] = __builtin_amdgcn_mfma_f32_32x32x16_bf16(af[ms][ks], bfm[ks], acc[ms], 0, 0, 0);
    }

    const int a = wn * 32 + l31;
    const float bb = bias[a];
    const int b = m0 >> 11;
    const int sb = (m0 & (SLEN - 1)) + wm * 64;
    const int bh = b * HHEADS + h;

    if (which == 0) {
        short* Ob = Out + (size_t)bh * SLEN * 64;
#pragma unroll
        for (int ms = 0; ms < 2; ++ms)
#pragma unroll
            for (int r = 0; r < 16; ++r) {
                int s = sb + ms * 32 + (r & 3) + 8 * (r >> 2) + 4 * hi;
                Ob[(size_t)s * 64 + a] = (short)f2bf((acc[ms][r] + bb) * EXPC);
            }
    } else if (which == 1) {
        short* Ob = Out + (size_t)bh * SLEN * 64;
#pragma unroll
        for (int ms = 0; ms < 2; ++ms)
#pragma unroll
            for (int r = 0; r < 16; ++r) {
                int s = sb + ms * 32 + (r & 3) + 8 * (r >> 2) + 4 * hi;
                Ob[(size_t)s * 64 + a] = (short)f2bf(acc[ms][r] + bb);
            }
    } else {
        short* Ob = Out + ((size_t)bh * 64 + a) * SLEN;
#pragma unroll
        for (int ms = 0; ms < 2; ++ms)
#pragma unroll
            for (int g = 0; g < 4; ++g) {
                int s = sb + ms * 32 + 8 * g + 4 * hi;
                ushort4 w;
                w.x = f2bf(acc[ms][4 * g + 0] + bb);
                w.y = f2bf(acc[ms][4 * g + 1] + bb);
                w.z = f2bf(acc[ms][4 * g + 2] + bb);
                w.w = f2bf(acc[ms][4 * g + 3] + bb);
                *(ushort4*)&Ob[s] = w;
            }
    }
}

// ---------------------------------------------------------------------------
// attn v4: 512 blocks = (qt 32 x bh 16), 2 blocks/CU. 4 waves = 2 wq (32-q
// subtiles) x 2 wk (1024-key halves). Both halves' K/V tiles LDS-staged per
// kt (each tile consumed by the 2 wq waves of that half -> staging reuse
// preserved), 16 kt iterations, reg double-buffer. fp32 2-way merge across
// wk in LDS, normalized bf16 written DIRECTLY to hc (no Opart/lpart/merge).
// XCD swizzle: 2 bh per XCD. Inner math verbatim R1/R5 (refcheck-passing).
// ---------------------------------------------------------------------------
__global__ __launch_bounds__(256, 2) void attn_mfma(
    const short* __restrict__ Qb, const short* __restrict__ Kb,
    const short* __restrict__ Vtb, short* __restrict__ hc)
{
    __shared__ union {
        struct { short Ks[2][64 * 72]; short Vs[2][64 * 72]; } st;  // 36 KB
        struct { float Om[2][32][66]; float Lm[2][32]; } mg;        // 17 KB
    } shm;

    const int tid = threadIdx.x;
    const int wid = tid >> 6;
    const int wq = wid & 1, wk = wid >> 1;
    const int lane = tid & 63;
    const int l31 = lane & 31;
    const int hi = lane >> 5;

    const int bidx = blockIdx.x;                  // 512 blocks
    const int swz = (bidx & 7) * 64 + (bidx >> 3);
    const int qt = swz & 31, bh = swz >> 5;

    const short* Qg = Qb + (size_t)bh * SLEN * 64;
    const short* Kg = Kb + (size_t)bh * SLEN * 64;
    const short* Vg = Vtb + (size_t)bh * 64 * SLEN;

    const int q0 = qt * 64 + wq * 32;

    short8 qf[4];
#pragma unroll
    for (int ks = 0; ks < 4; ++ks)
        qf[ks] = *(const short8*)&Qg[(size_t)(q0 + l31) * 64 + ks * 16 + hi * 8];

    f32x16 oacc[2];
    float lsum = 0.f;
#pragma unroll
    for (int dt = 0; dt < 2; ++dt)
#pragma unroll
        for (int r = 0; r < 16; ++r) oacc[dt][r] = 0.f;

    const int srow = tid >> 2;
    const int sch = (tid & 3) * 16;

    // prologue: stage tile 0 of both halves into registers
    short8 rk[2][2], rv[2][2];
#pragma unroll
    for (int h = 0; h < 2; ++h) {
        rk[h][0] = *(const short8*)&Kg[(size_t)(h * 1024 + srow) * 64 + sch];
        rk[h][1] = *(const short8*)&Kg[(size_t)(h * 1024 + srow) * 64 + sch + 8];
        rv[h][0] = *(const short8*)&Vg[(size_t)srow * SLEN + h * 1024 + sch];
        rv[h][1] = *(const short8*)&Vg[(size_t)srow * SLEN + h * 1024 + sch + 8];
    }

#pragma unroll 1
    for (int kt = 0; kt < 16; ++kt) {
        __syncthreads();
#pragma unroll
        for (int h = 0; h < 2; ++h) {
            *(short8*)&shm.st.Ks[h][srow * 72 + sch]     = rk[h][0];
            *(short8*)&shm.st.Ks[h][srow * 72 + sch + 8] = rk[h][1];
            *(short8*)&shm.st.Vs[h][srow * 72 + sch]     = rv[h][0];
            *(short8*)&shm.st.Vs[h][srow * 72 + sch + 8] = rv[h][1];
        }
        __syncthreads();

        if (kt < 15) {
            const int k0n = (kt + 1) * 64;
#pragma unroll
            for (int h = 0; h < 2; ++h) {
                rk[h][0] = *(const short8*)&Kg[(size_t)(h * 1024 + k0n + srow) * 64 + sch];
                rk[h][1] = *(const short8*)&Kg[(size_t)(h * 1024 + k0n + srow) * 64 + sch + 8];
                rv[h][0] = *(const short8*)&Vg[(size_t)srow * SLEN + h * 1024 + k0n + sch];
                rv[h][1] = *(const short8*)&Vg[(size_t)srow * SLEN + h * 1024 + k0n + sch + 8];
            }
        }

        short8 kf[2][4], vf[2][4];
#pragma unroll
        for (int mt = 0; mt < 2; ++mt)
#pragma unroll
            for (int ks = 0; ks < 4; ++ks)
                kf[mt][ks] = *(const short8*)&shm.st.Ks[wk][(mt * 32 + l31) * 72 + ks * 16 + hi * 8];
#pragma unroll
        for (int dt = 0; dt < 2; ++dt)
#pragma unroll
            for (int p = 0; p < 4; ++p)
                vf[dt][p] = *(const short8*)&shm.st.Vs[wk][(dt * 32 + l31) * 72 + p * 16 + hi * 8];

        f32x16 sacc[2];
        __builtin_amdgcn_s_setprio(1);
#pragma unroll
        for (int mt = 0; mt < 2; ++mt) {
            f32x16 s;
#pragma unroll
            for (int r = 0; r < 16; ++r) s[r] = 0.f;
#pragma unroll
            for (int ks = 0; ks < 4; ++ks)
                s = __builtin_amdgcn_mfma_f32_32x32x16_bf16(kf[mt][ks], qf[ks], s, 0, 0, 0);
            sacc[mt] = s;
        }
        __builtin_amdgcn_s_setprio(0);

        // p = exp2(s); pack via v_perm truncation; VALU lsum on the SAME
        // truncated values (numerator/denominator rounding matched).
        int2 pk[2][4];
#pragma unroll
        for (int mt = 0; mt < 2; ++mt)
#pragma unroll
            for (int g = 0; g < 4; ++g) {
                unsigned a0 = __float_as_uint(__builtin_amdgcn_exp2f(sacc[mt][4 * g + 0]));
                unsigned a1 = __float_as_uint(__builtin_amdgcn_exp2f(sacc[mt][4 * g + 1]));
                unsigned a2 = __float_as_uint(__builtin_amdgcn_exp2f(sacc[mt][4 * g + 2]));
                unsigned a3 = __float_as_uint(__builtin_amdgcn_exp2f(sacc[mt][4 * g + 3]));
                float t0 = __uint_as_float(a0 & 0xffff0000u);
                float t1 = __uint_as_float(a1 & 0xffff0000u);
                float t2 = __uint_as_float(a2 & 0xffff0000u);
                float t3 = __uint_as_float(a3 & 0xffff0000u);
                lsum += (t0 + t1) + (t2 + t3);
                pk[mt][g].x = (int)__builtin_amdgcn_perm(a1, a0, 0x07060302u);
                pk[mt][g].y = (int)__builtin_amdgcn_perm(a3, a2, 0x07060302u);
            }

        // minimal cross-half exchange: partner needs pk[2h2 + (1-hi)]
        int2 xch[2][2];
#pragma unroll
        for (int mt = 0; mt < 2; ++mt)
#pragma unroll
            for (int h2 = 0; h2 < 2; ++h2) {
                int2 v = hi ? pk[mt][2 * h2] : pk[mt][2 * h2 + 1];
                xch[mt][h2].x = __shfl_xor(v.x, 32);
                xch[mt][h2].y = __shfl_xor(v.y, 32);
            }

        __builtin_amdgcn_s_setprio(1);
#pragma unroll
        for (int p = 0; p < 4; ++p) {
            const int mt = p >> 1, h2 = p & 1;
            const int ga = 2 * h2, gb = 2 * h2 + 1;
            const int2 X = xch[mt][h2];
            union { int4 i; short8 s; } u;
            u.i.x = hi ? X.x : pk[mt][ga].x;
            u.i.y = hi ? X.y : pk[mt][ga].y;
            u.i.z = hi ? pk[mt][gb].x : X.x;
            u.i.w = hi ? pk[mt][gb].y : X.y;
#pragma unroll
            for (int dt = 0; dt < 2; ++dt)
                oacc[dt] = __builtin_amdgcn_mfma_f32_32x32x16_bf16(u.s, vf[dt][p], oacc[dt], 0, 0, 0);
        }
        __builtin_amdgcn_s_setprio(0);
    }

    // ---- fp32 2-way merge across wk halves, direct normalized hc write ----
    const float lt = lsum + __shfl_xor(lsum, 32);   // lane l: l_half[q0 + l31]
    __syncthreads();                                 // all st reads done
    if (wk == 1) {
#pragma unroll
        for (int dt = 0; dt < 2; ++dt)
#pragma unroll
            for (int r = 0; r < 16; ++r) {
                int qrow = (r & 3) + 8 * (r >> 2) + 4 * hi;
                shm.mg.Om[wq][qrow][dt * 32 + l31] = oacc[dt][r];
            }
        if (hi == 0) shm.mg.Lm[wq][l31] = lt;
    }
    __syncthreads();
    if (wk == 0) {
        const float inv = 1.f / (lt + shm.mg.Lm[wq][l31]);
        const int b = bh >> 3, h = bh & 7;
#pragma unroll
        for (int r = 0; r < 16; ++r) {
            const int qrow = (r & 3) + 8 * (r >> 2) + 4 * hi;
            const float iv = __shfl(inv, qrow);     // 1/l for row q0+qrow
            const size_t rowb = ((size_t)(b * SLEN + q0 + qrow)) * DDIM + h * 64;
#pragma unroll
            for (int dt = 0; dt < 2; ++dt)
                hc[rowb + dt * 32 + l31] =
                    (short)f2bf((oacc[dt][r] + shm.mg.Om[wq][qrow][dt * 32 + l31]) * iv);
        }
    }
}

// ---------------------------------------------------------------------------
// AddNorm on bf16 stream (verbatim R1): xbf = LN(xbf + y) * g + b ; y fp32.
// ---------------------------------------------------------------------------
__global__ __launch_bounds__(256) void addnorm_bf(
    short* __restrict__ X, const float* __restrict__ Y,
    const float* __restrict__ g, const float* __restrict__ beta)
{
    const int lane = threadIdx.x & 63;
    const int t = blockIdx.x * 4 + (threadIdx.x >> 6);
    short* xr = X + (size_t)t * DDIM;
    const float* yr = Y + (size_t)t * DDIM;
    const int c0 = lane * 8;

    short8 x8 = *(const short8*)&xr[c0];
    float4 y0 = *(const float4*)&yr[c0];
    float4 y1 = *(const float4*)&yr[c0 + 4];
    float v[8];
    v[0] = bf2f(x8[0]) + y0.x; v[1] = bf2f(x8[1]) + y0.y;
    v[2] = bf2f(x8[2]) + y0.z; v[3] = bf2f(x8[3]) + y0.w;
    v[4] = bf2f(x8[4]) + y1.x; v[5] = bf2f(x8[5]) + y1.y;
    v[6] = bf2f(x8[6]) + y1.z; v[7] = bf2f(x8[7]) + y1.w;

    float s1 = 0.f, s2 = 0.f;
#pragma unroll
    for (int j = 0; j < 8; ++j) { s1 += v[j]; s2 += v[j] * v[j]; }
#pragma unroll
    for (int off = 1; off < 64; off <<= 1) {
        s1 += __shfl_xor(s1, off);
        s2 += __shfl_xor(s2, off);
    }
    float mean = s1 * (1.0f / DDIM);
    float var = s2 * (1.0f / DDIM) - mean * mean;
    float rstd = rsqrtf(var + 1e-5f);

    float4 ga = *(const float4*)&g[c0];
    float4 gb = *(const float4*)&g[c0 + 4];
    float4 ba = *(const float4*)&beta[c0];
    float4 bb = *(const float4*)&beta[c0 + 4];
    float gg[8] = {ga.x, ga.y, ga.z, ga.w, gb.x, gb.y, gb.z, gb.w};
    float bt[8] = {ba.x, ba.y, ba.z, ba.w, bb.x, bb.y, bb.z, bb.w};

    short8 o8;
#pragma unroll
    for (int j = 0; j < 8; ++j)
        o8[j] = (short)f2bf((v[j] - mean) * rstd * gg[j] + bt[j]);
    *(short8*)&xr[c0] = o8;
}

// ---------------------------------------------------------------------------
// Workspace (MiB), lifetime-checked, < 40 MiB:
//   [ 0, 4) xbf   [ 4, 8) Qbuf   [ 8,12) Kbuf   [12,16) Vtbuf
//   [16,20) hcbf (separate: attn reads Q while writing hc)
//   [20,28) y fp32   [28,32) hidbf   [33,39.25) weights bf16
// ---------------------------------------------------------------------------
extern "C" void kernel_launch(void* const* d_in, const int* in_sizes, int n_in,
                              void* d_out, int out_size, void* d_ws, size_t ws_size,
                              hipStream_t stream)
{
    (void)in_sizes; (void)n_in; (void)out_size; (void)ws_size;
    const float* x   = (const float*)d_in[0];
    const float* Wq  = (const float*)d_in[1];
    const float* bq  = (const float*)d_in[2];
    const float* Wk  = (const float*)d_in[3];
    const float* bk  = (const float*)d_in[4];
    const float* Wv  = (const float*)d_in[5];
    const float* bv  = (const float*)d_in[6];
    const float* Wo  = (const float*)d_in[7];
    const float* bo  = (const float*)d_in[8];
    const float* g1  = (const float*)d_in[9];
    const float* be1 = (const float*)d_in[10];
    const float* W1  = (const float*)d_in[11];
    const float* b1  = (const float*)d_in[12];
    const float* W2  = (const float*)d_in[13];
    const float* b2  = (const float*)d_in[14];
    const float* g2  = (const float*)d_in[15];
    const float* be2 = (const float*)d_in[16];
    const float* Wp  = (const float*)d_in[17];
    const float* bp  = (const float*)d_in[18];

    char* wsb = (char*)d_ws;
    const size_t MB = 1024 * 1024;
    short* xbf   = (short*)(wsb + 0);
    short* Qbuf  = (short*)(wsb + 4 * MB);
    short* Kbuf  = (short*)(wsb + 8 * MB);
    short* Vtbuf = (short*)(wsb + 12 * MB);
    short* hcbf  = (short*)(wsb + 16 * MB);
    float* y     = (float*)(wsb + 20 * MB);
    short* hidbf = (short*)(wsb + 28 * MB);
    short* Wqt   = (short*)(wsb + 33 * MB);
    short* Wkt   = (short*)(wsb + 34 * MB);
    short* Wvt   = (short*)(wsb + 35 * MB);
    short* Wot   = (short*)(wsb + 36 * MB);
    short* W1t   = (short*)(wsb + 37 * MB);
    short* W2t   = (short*)(wsb + 38 * MB);
    short* Wpt   = (short*)(wsb + 39 * MB);

    prep_k<<<1056, 256, 0, stream>>>(Wq, Wk, Wv, Wo, W1, W2, Wp, x,
                                     Wqt, Wkt, Wvt, Wot, W1t, W2t, Wpt, xbf);

    for (int i = 0; i < 2; ++i) {
        const size_t wOff = (size_t)i * 262144;
        qkv_bf<<<dim3(24, 32), 256, 0, stream>>>(
            xbf, Wqt + wOff, Wkt + wOff, Wvt + wOff,
            bq + i * 512, bk + i * 512, bv + i * 512,
            Qbuf, Kbuf, Vtbuf);
        attn_mfma<<<512, 256, 0, stream>>>(Qbuf, Kbuf, Vtbuf, hcbf);
        gemm_bf<<<dim3(8, 64), 256, 0, stream>>>(
            hcbf, Wot + wOff, bo + i * 512, y, MDIM, DDIM, DDIM, 0);
        addnorm_bf<<<1024, 256, 0, stream>>>(xbf, y, g1 + i * 512, be1 + i * 512);
        gemm_bf<<<dim3(8, 64), 256, 0, stream>>>(
            xbf, W1t + wOff, b1 + i * 512, hidbf, MDIM, DDIM, DDIM, 3);
        gemm_bf<<<dim3(8, 64), 256, 0, stream>>>(
            hidbf, W2t + wOff, b2 + i * 512, y, MDIM, DDIM, DDIM, 0);
        addnorm_bf<<<1024, 256, 0, stream>>>(xbf, y, g2 + i * 512, be2 + i * 512);
    }
    gemm_bf<<<dim3(4, 64), 256, 0, stream>>>(
        xbf, Wpt, bp, (float*)d_out, MDIM, TDIM, DDIM, 0);
}

// Round 7
// 280.942 us; speedup vs baseline: 6.7987x; 1.1650x over previous
//
#include <hip/hip_runtime.h>
#include <hip/hip_bf16.h>

#define MDIM 4096      // B*S tokens
#define DDIM 512
#define HHEADS 8
#define SLEN 2048
#define TDIM 256
#define SPLIT 4
#define LDT 66
#define LDA 66         // attn LDS stride: 33 dwords -> bank = l31, conflict-free
#define EXPC 0.1803368801111244f   // 0.125 * log2(e)

typedef __attribute__((ext_vector_type(8))) short short8;
typedef __attribute__((ext_vector_type(16))) float f32x16;

__device__ __forceinline__ unsigned short f2bf(float f) {
    union { __hip_bfloat16 h; unsigned short u; } c;
    c.h = __float2bfloat16(f);
    return c.u;
}
__device__ __forceinline__ float bf2f(short s) {
    return __uint_as_float((unsigned)(unsigned short)s << 16);
}

// ---------------------------------------------------------------------------
// prep (R5, coalesced both ways): LDS-tiled 64x64 transposes.
// ---------------------------------------------------------------------------
__global__ __launch_bounds__(256) void prep_k(
    const float* __restrict__ Wq, const float* __restrict__ Wk, const float* __restrict__ Wv,
    const float* __restrict__ Wo, const float* __restrict__ W1, const float* __restrict__ W2,
    const float* __restrict__ Wp, const float* __restrict__ x,
    short* __restrict__ Wqt, short* __restrict__ Wkt, short* __restrict__ Wvt,
    short* __restrict__ Wot, short* __restrict__ W1t, short* __restrict__ W2t,
    short* __restrict__ Wpt, short* __restrict__ xbf)
{
    __shared__ short T[64][72];
    const int b = blockIdx.x, tid = threadIdx.x;

    if (b >= 800) {
        const int idx = (b - 800) * 256 + tid;
        for (int e = idx; e < 262144; e += 65536) {
            float4 f0 = *(const float4*)&x[e * 8];
            float4 f1 = *(const float4*)&x[e * 8 + 4];
            short8 o;
            o[0] = (short)f2bf(f0.x); o[1] = (short)f2bf(f0.y);
            o[2] = (short)f2bf(f0.z); o[3] = (short)f2bf(f0.w);
            o[4] = (short)f2bf(f1.x); o[5] = (short)f2bf(f1.y);
            o[6] = (short)f2bf(f1.z); o[7] = (short)f2bf(f1.w);
            *(short8*)&xbf[e * 8] = o;
        }
        return;
    }

    const float* srcp; short* dstp; int ss;
    if (b < 384) {
        int w = b >> 7, t = b & 127;
        int lh = t >> 3, kt0 = (t & 7) << 6;
        const float* W = (w == 0) ? Wq : (w == 1) ? Wk : Wv;
        short* Wt = (w == 0) ? Wqt : (w == 1) ? Wkt : Wvt;
        srcp = W + (size_t)lh * 32768 + (size_t)kt0 * 64;
        dstp = Wt + (size_t)lh * 32768 + kt0;
        ss = 64;
    } else if (b < 768) {
        int w = (b - 384) >> 7, t = (b - 384) & 127;
        int l = t >> 6, tt = t & 63;
        int kt0 = (tt >> 3) << 6, nt0 = (tt & 7) << 6;
        const float* W = (w == 0) ? Wo : (w == 1) ? W1 : W2;
        short* Wt = (w == 0) ? Wot : (w == 1) ? W1t : W2t;
        srcp = W + (size_t)l * 262144 + (size_t)kt0 * 512 + nt0;
        dstp = Wt + (size_t)l * 262144 + (size_t)nt0 * 512 + kt0;
        ss = 512;
    } else {
        int t = b - 768;
        int kt0 = (t >> 2) << 6, nt0 = (t & 3) << 6;
        srcp = Wp + (size_t)kt0 * 256 + nt0;
        dstp = Wpt + (size_t)nt0 * 512 + kt0;
        ss = 256;
    }

    const int r = tid >> 2, c0 = (tid & 3) * 16;
#pragma unroll
    for (int j = 0; j < 16; j += 4) {
        float4 f = *(const float4*)&srcp[(size_t)r * ss + c0 + j];
        T[r][c0 + j + 0] = (short)f2bf(f.x);
        T[r][c0 + j + 1] = (short)f2bf(f.y);
        T[r][c0 + j + 2] = (short)f2bf(f.z);
        T[r][c0 + j + 3] = (short)f2bf(f.w);
    }
    __syncthreads();
    short8 o0, o1;
#pragma unroll
    for (int j = 0; j < 8; ++j) { o0[j] = T[c0 + j][r]; o1[j] = T[c0 + 8 + j][r]; }
    *(short8*)&dstp[(size_t)r * 512 + c0] = o0;
    *(short8*)&dstp[(size_t)r * 512 + c0 + 8] = o1;
}

// ---------------------------------------------------------------------------
// bf16 MFMA GEMM (verbatim R0, proven): C[M,N] = A[M,K] @ B + bias.
// Bt[n][k]. Tile 64m x 64n, BK=64, 4 waves (2m x 2n).
// flags: 1=relu, 2=bf16 out.
// ---------------------------------------------------------------------------
__global__ __launch_bounds__(256, 2) void gemm_bf(
    const short* __restrict__ A, const short* __restrict__ Bt,
    const float* __restrict__ bias, void* __restrict__ Cout,
    int M, int N, int K, int flags)
{
    __shared__ short As[64 * LDT];
    __shared__ short Bs[64 * LDT];
    const int tid = threadIdx.x;
    const int wave = tid >> 6, lane = tid & 63;
    const int l31 = lane & 31, hi = lane >> 5;
    const int wm = wave >> 1, wn = wave & 1;
    const int m0 = blockIdx.y * 64, n0 = blockIdx.x * 64;

    f32x16 acc;
#pragma unroll
    for (int r = 0; r < 16; ++r) acc[r] = 0.f;

    const int sr = tid >> 2;          // 0..63
    const int sc = (tid & 3) * 16;    // short chunk

    for (int k0 = 0; k0 < K; k0 += 64) {
        __syncthreads();
        *(short8*)&As[sr * LDT + sc]     = *(const short8*)&A[(size_t)(m0 + sr) * K + k0 + sc];
        *(short8*)&As[sr * LDT + sc + 8] = *(const short8*)&A[(size_t)(m0 + sr) * K + k0 + sc + 8];
        *(short8*)&Bs[sr * LDT + sc]     = *(const short8*)&Bt[(size_t)(n0 + sr) * K + k0 + sc];
        *(short8*)&Bs[sr * LDT + sc + 8] = *(const short8*)&Bt[(size_t)(n0 + sr) * K + k0 + sc + 8];
        __syncthreads();

        short8 af[4], bfm[4];
#pragma unroll
        for (int ks = 0; ks < 4; ++ks) {
            af[ks]  = *(const short8*)&As[(wm * 32 + l31) * LDT + ks * 16 + hi * 8];
            bfm[ks] = *(const short8*)&Bs[(wn * 32 + l31) * LDT + ks * 16 + hi * 8];
        }
#pragma unroll
        for (int ks = 0; ks < 4; ++ks)
            acc = __builtin_amdgcn_mfma_f32_32x32x16_bf16(af[ks], bfm[ks], acc, 0, 0, 0);
    }

    const int col = n0 + wn * 32 + l31;
    const float bb = bias[col];
    const int rbase = m0 + wm * 32 + 4 * hi;
#pragma unroll
    for (int r = 0; r < 16; ++r) {
        int row = rbase + (r & 3) + 8 * (r >> 2);
        float v = acc[r] + bb;
        if (flags & 1) v = fmaxf(v, 0.f);
        if (flags & 2) ((short*)Cout)[(size_t)row * N + col] = (short)f2bf(v);
        else           ((float*)Cout)[(size_t)row * N + col] = v;
    }
}

// ---------------------------------------------------------------------------
// Fused QKV MFMA GEMM (verbatim R1): A=xbf [4096,512]; grid (24, 32).
// Q pre-scaled by 0.125*log2(e); Q,K [bh][s][64] bf16; V transposed [bh][d][s].
// ---------------------------------------------------------------------------
__global__ __launch_bounds__(256, 2) void qkv_bf(
    const short* __restrict__ A,
    const short* __restrict__ Wqt, const short* __restrict__ Wkt, const short* __restrict__ Wvt,
    const float* __restrict__ bq, const float* __restrict__ bk, const float* __restrict__ bv,
    short* __restrict__ Oq, short* __restrict__ Ok, short* __restrict__ Ov)
{
    __shared__ short As[128 * LDT];
    __shared__ short Bs[64 * LDT];
    const int tid = threadIdx.x;
    const int wave = tid >> 6, lane = tid & 63;
    const int l31 = lane & 31, hi = lane >> 5;
    const int wm = wave >> 1, wn = wave & 1;
    const int m0 = blockIdx.y * 128;
    const int nt = blockIdx.x;
    const int which = nt >> 3, h = nt & 7;

    const short* Bt = ((which == 0) ? Wqt : (which == 1) ? Wkt : Wvt) + (size_t)h * 64 * 512;
    const float* bias = ((which == 0) ? bq : (which == 1) ? bk : bv) + h * 64;
    short* Out = (which == 0) ? Oq : (which == 1) ? Ok : Ov;

    f32x16 acc[2];
#pragma unroll
    for (int ms = 0; ms < 2; ++ms)
#pragma unroll
        for (int r = 0; r < 16; ++r) acc[ms][r] = 0.f;

    const int sr = tid >> 3;
    const int sc = (tid & 7) * 8;

    for (int k0 = 0; k0 < 512; k0 += 64) {
        __syncthreads();
#pragma unroll
        for (int p = 0; p < 4; ++p)
            *(short8*)&As[(p * 32 + sr) * LDT + sc] =
                *(const short8*)&A[(size_t)(m0 + p * 32 + sr) * 512 + k0 + sc];
#pragma unroll
        for (int p = 0; p < 2; ++p)
            *(short8*)&Bs[(p * 32 + sr) * LDT + sc] =
                *(const short8*)&Bt[(size_t)(p * 32 + sr) * 512 + k0 + sc];
        __syncthreads();

        short8 af[2][4], bfm[4];
#pragma unroll
        for (int ms = 0; ms < 2; ++ms)
#pragma unroll
            for (int ks = 0; ks < 4; ++ks)
                af[ms][ks] = *(const short8*)&As[(wm * 64 + ms * 32 + l31) * LDT + ks * 16 + hi * 8];
#pragma unroll
        for (int ks = 0; ks < 4; ++ks)
            bfm[ks] = *(const short8*)&Bs[(wn * 32 + l31) * LDT + ks * 16 + hi * 8];
#pragma unroll
        for (int ms = 0; ms < 2; ++ms)
#pragma unroll
            for (int ks = 0; ks < 4; ++ks)
                acc[ms] = __builtin_amdgcn_mfma_f32_32x32x16_bf16(af[ms][ks], bfm[ks], acc[ms], 0, 0, 0);
    }

    const int a = wn * 32 + l31;
    const float bb = bias[a];
    const int b = m0 >> 11;
    const int sb = (m0 & (SLEN - 1)) + wm * 64;
    const int bh = b * HHEADS + h;

    if (which == 0) {
        short* Ob = Out + (size_t)bh * SLEN * 64;
#pragma unroll
        for (int ms = 0; ms < 2; ++ms)
#pragma unroll
            for (int r = 0; r < 16; ++r) {
                int s = sb + ms * 32 + (r & 3) + 8 * (r >> 2) + 4 * hi;
                Ob[(size_t)s * 64 + a] = (short)f2bf((acc[ms][r] + bb) * EXPC);
            }
    } else if (which == 1) {
        short* Ob = Out + (size_t)bh * SLEN * 64;
#pragma unroll
        for (int ms = 0; ms < 2; ++ms)
#pragma unroll
            for (int r = 0; r < 16; ++r) {
                int s = sb + ms * 32 + (r & 3) + 8 * (r >> 2) + 4 * hi;
                Ob[(size_t)s * 64 + a] = (short)f2bf(acc[ms][r] + bb);
            }
    } else {
        short* Ob = Out + ((size_t)bh * 64 + a) * SLEN;
#pragma unroll
        for (int ms = 0; ms < 2; ++ms)
#pragma unroll
            for (int g = 0; g < 4; ++g) {
                int s = sb + ms * 32 + 8 * g + 4 * hi;
                ushort4 w;
                w.x = f2bf(acc[ms][4 * g + 0] + bb);
                w.y = f2bf(acc[ms][4 * g + 1] + bb);
                w.z = f2bf(acc[ms][4 * g + 2] + bb);
                w.w = f2bf(acc[ms][4 * g + 3] + bb);
                *(ushort4*)&Ob[s] = w;
            }
    }
}

// ---------------------------------------------------------------------------
// attn (R1 structure, q-heavy 256q x 512k per block, key-split=4) with ONE
// change: LDS stride 72 -> 66 (33 dwords: bank = l31, conflict-free; the 72
// stride was a 4-way conflict on every ds_read_b128 = ~31us/dispatch, R6 PMC).
// ---------------------------------------------------------------------------
__global__ __launch_bounds__(256, 2) void attn_mfma(
    const short* __restrict__ Qb, const short* __restrict__ Kb,
    const short* __restrict__ Vtb, short* __restrict__ Op,
    float* __restrict__ lp)
{
    __shared__ short Ks[64 * LDA];
    __shared__ short Vs[64 * LDA];

    const int tid = threadIdx.x;
    const int wid = tid >> 6;
    const int lane = tid & 63;
    const int l31 = lane & 31;
    const int hi = lane >> 5;

    const int qt = blockIdx.x;
    const int bh = blockIdx.y;
    const int sp = blockIdx.z;

    const short* Qg = Qb + (size_t)bh * SLEN * 64;
    const short* Kg = Kb + (size_t)bh * SLEN * 64;
    const short* Vg = Vtb + (size_t)bh * 64 * SLEN;

    const int q0 = qt * 256 + wid * 64;

    short8 qf[2][4];
#pragma unroll
    for (int nt = 0; nt < 2; ++nt)
#pragma unroll
        for (int ks = 0; ks < 4; ++ks)
            qf[nt][ks] = *(const short8*)&Qg[(size_t)(q0 + nt * 32 + l31) * 64 + ks * 16 + hi * 8];

    f32x16 oacc[2][2];
    float lsum[2] = {0.f, 0.f};
#pragma unroll
    for (int nt = 0; nt < 2; ++nt)
#pragma unroll
        for (int dt = 0; dt < 2; ++dt)
#pragma unroll
            for (int r = 0; r < 16; ++r) oacc[nt][dt][r] = 0.f;

    const int srow = tid >> 2;
    const int sch = (tid & 3) * 16;
    const int kbase = sp * (SLEN / SPLIT);

    // prologue: stage tile 0 into registers
    short8 rk0 = *(const short8*)&Kg[(size_t)(kbase + srow) * 64 + sch];
    short8 rk1 = *(const short8*)&Kg[(size_t)(kbase + srow) * 64 + sch + 8];
    short8 rv0 = *(const short8*)&Vg[(size_t)srow * SLEN + kbase + sch];
    short8 rv1 = *(const short8*)&Vg[(size_t)srow * SLEN + kbase + sch + 8];

#pragma unroll 1
    for (int kt = 0; kt < 8; ++kt) {
        __syncthreads();
        *(short8*)&Ks[srow * LDA + sch]     = rk0;
        *(short8*)&Ks[srow * LDA + sch + 8] = rk1;
        *(short8*)&Vs[srow * LDA + sch]     = rv0;
        *(short8*)&Vs[srow * LDA + sch + 8] = rv1;
        __syncthreads();

        if (kt < 7) {
            const int k0n = kbase + (kt + 1) * 64;
            rk0 = *(const short8*)&Kg[(size_t)(k0n + srow) * 64 + sch];
            rk1 = *(const short8*)&Kg[(size_t)(k0n + srow) * 64 + sch + 8];
            rv0 = *(const short8*)&Vg[(size_t)srow * SLEN + k0n + sch];
            rv1 = *(const short8*)&Vg[(size_t)srow * SLEN + k0n + sch + 8];
        }

        short8 kf[2][4], vf[2][4];
#pragma unroll
        for (int mt = 0; mt < 2; ++mt)
#pragma unroll
            for (int ks = 0; ks < 4; ++ks)
                kf[mt][ks] = *(const short8*)&Ks[(mt * 32 + l31) * LDA + ks * 16 + hi * 8];
#pragma unroll
        for (int dt = 0; dt < 2; ++dt)
#pragma unroll
            for (int p = 0; p < 4; ++p)
                vf[dt][p] = *(const short8*)&Vs[(dt * 32 + l31) * LDA + p * 16 + hi * 8];

#pragma unroll
        for (int nt = 0; nt < 2; ++nt) {
            f32x16 sacc[2];
            __builtin_amdgcn_s_setprio(1);
#pragma unroll
            for (int mt = 0; mt < 2; ++mt) {
                f32x16 s;
#pragma unroll
                for (int r = 0; r < 16; ++r) s[r] = 0.f;
#pragma unroll
                for (int ks = 0; ks < 4; ++ks)
                    s = __builtin_amdgcn_mfma_f32_32x32x16_bf16(kf[mt][ks], qf[nt][ks], s, 0, 0, 0);
                sacc[mt] = s;
            }
            __builtin_amdgcn_s_setprio(0);

            // p = exp2(s); pack via v_perm truncation; VALU lsum on the SAME
            // truncated values (numerator/denominator rounding matched).
            int2 pk[2][4];
#pragma unroll
            for (int mt = 0; mt < 2; ++mt)
#pragma unroll
                for (int g = 0; g < 4; ++g) {
                    unsigned a0 = __float_as_uint(__builtin_amdgcn_exp2f(sacc[mt][4 * g + 0]));
                    unsigned a1 = __float_as_uint(__builtin_amdgcn_exp2f(sacc[mt][4 * g + 1]));
                    unsigned a2 = __float_as_uint(__builtin_amdgcn_exp2f(sacc[mt][4 * g + 2]));
                    unsigned a3 = __float_as_uint(__builtin_amdgcn_exp2f(sacc[mt][4 * g + 3]));
                    float t0 = __uint_as_float(a0 & 0xffff0000u);
                    float t1 = __uint_as_float(a1 & 0xffff0000u);
                    float t2 = __uint_as_float(a2 & 0xffff0000u);
                    float t3 = __uint_as_float(a3 & 0xffff0000u);
                    lsum[nt] += (t0 + t1) + (t2 + t3);
                    pk[mt][g].x = (int)__builtin_amdgcn_perm(a1, a0, 0x07060302u);
                    pk[mt][g].y = (int)__builtin_amdgcn_perm(a3, a2, 0x07060302u);
                }

            int2 xch[2][2];
#pragma unroll
            for (int mt = 0; mt < 2; ++mt)
#pragma unroll
                for (int h2 = 0; h2 < 2; ++h2) {
                    int2 v = hi ? pk[mt][2 * h2] : pk[mt][2 * h2 + 1];
                    xch[mt][h2].x = __shfl_xor(v.x, 32);
                    xch[mt][h2].y = __shfl_xor(v.y, 32);
                }

            __builtin_amdgcn_s_setprio(1);
#pragma unroll
            for (int p = 0; p < 4; ++p) {
                const int mt = p >> 1, h2 = p & 1;
                const int ga = 2 * h2, gb = 2 * h2 + 1;
                const int2 X = xch[mt][h2];
                union { int4 i; short8 s; } u;
                u.i.x = hi ? X.x : pk[mt][ga].x;
                u.i.y = hi ? X.y : pk[mt][ga].y;
                u.i.z = hi ? pk[mt][gb].x : X.x;
                u.i.w = hi ? pk[mt][gb].y : X.y;
#pragma unroll
                for (int dt = 0; dt < 2; ++dt)
                    oacc[nt][dt] = __builtin_amdgcn_mfma_f32_32x32x16_bf16(u.s, vf[dt][p], oacc[nt][dt], 0, 0, 0);
            }
            __builtin_amdgcn_s_setprio(0);
        }
    }

#pragma unroll
    for (int nt = 0; nt < 2; ++nt) {
        float lt = lsum[nt] + __shfl_xor(lsum[nt], 32);
        if (hi == 0)
            lp[((size_t)(sp * 16 + bh)) * SLEN + q0 + nt * 32 + l31] = lt;
#pragma unroll
        for (int dt = 0; dt < 2; ++dt) {
#pragma unroll
            for (int r = 0; r < 16; ++r) {
                int qrow = (r & 3) + 8 * (r >> 2) + 4 * hi;
                size_t addr = (((size_t)(sp * 16 + bh)) * SLEN + (q0 + nt * 32 + qrow)) * 64 + dt * 32 + l31;
                Op[addr] = (short)f2bf(oacc[nt][dt][r]);
            }
        }
    }
}

// ---------------------------------------------------------------------------
// Merge key-split partials -> hc bf16 [b,s, h*64+d] (verbatim R1)
// ---------------------------------------------------------------------------
__global__ __launch_bounds__(256) void merge_k(
    const short* __restrict__ Op, const float* __restrict__ lp,
    short* __restrict__ hc)
{
    const int g = blockIdx.x * 256 + threadIdx.x;   // 512K threads
    const int d4 = g & 15;
    const int s = (g >> 4) & (SLEN - 1);
    const int bh = g >> 15;

    float o[4] = {0.f, 0.f, 0.f, 0.f};
    float ls = 0.f;
#pragma unroll
    for (int sp = 0; sp < SPLIT; ++sp) {
        const size_t base = (((size_t)(sp * 16 + bh)) * SLEN + s);
        ushort4 u4 = *(const ushort4*)&Op[base * 64 + d4 * 4];
        o[0] += bf2f((short)u4.x); o[1] += bf2f((short)u4.y);
        o[2] += bf2f((short)u4.z); o[3] += bf2f((short)u4.w);
        ls += lp[base];
    }
    const int b = bh >> 3, h = bh & 7;
    const float inv = 1.f / ls;
    ushort4 w;
    w.x = f2bf(o[0] * inv); w.y = f2bf(o[1] * inv);
    w.z = f2bf(o[2] * inv); w.w = f2bf(o[3] * inv);
    *(ushort4*)&hc[((size_t)(b * SLEN + s)) * DDIM + h * 64 + d4 * 4] = w;
}

// ---------------------------------------------------------------------------
// AddNorm on bf16 stream (verbatim R1): xbf = LN(xbf + y) * g + b ; y fp32.
// ---------------------------------------------------------------------------
__global__ __launch_bounds__(256) void addnorm_bf(
    short* __restrict__ X, const float* __restrict__ Y,
    const float* __restrict__ g, const float* __restrict__ beta)
{
    const int lane = threadIdx.x & 63;
    const int t = blockIdx.x * 4 + (threadIdx.x >> 6);
    short* xr = X + (size_t)t * DDIM;
    const float* yr = Y + (size_t)t * DDIM;
    const int c0 = lane * 8;

    short8 x8 = *(const short8*)&xr[c0];
    float4 y0 = *(const float4*)&yr[c0];
    float4 y1 = *(const float4*)&yr[c0 + 4];
    float v[8];
    v[0] = bf2f(x8[0]) + y0.x; v[1] = bf2f(x8[1]) + y0.y;
    v[2] = bf2f(x8[2]) + y0.z; v[3] = bf2f(x8[3]) + y0.w;
    v[4] = bf2f(x8[4]) + y1.x; v[5] = bf2f(x8[5]) + y1.y;
    v[6] = bf2f(x8[6]) + y1.z; v[7] = bf2f(x8[7]) + y1.w;

    float s1 = 0.f, s2 = 0.f;
#pragma unroll
    for (int j = 0; j < 8; ++j) { s1 += v[j]; s2 += v[j] * v[j]; }
#pragma unroll
    for (int off = 1; off < 64; off <<= 1) {
        s1 += __shfl_xor(s1, off);
        s2 += __shfl_xor(s2, off);
    }
    float mean = s1 * (1.0f / DDIM);
    float var = s2 * (1.0f / DDIM) - mean * mean;
    float rstd = rsqrtf(var + 1e-5f);

    float4 ga = *(const float4*)&g[c0];
    float4 gb = *(const float4*)&g[c0 + 4];
    float4 ba = *(const float4*)&beta[c0];
    float4 bb = *(const float4*)&beta[c0 + 4];
    float gg[8] = {ga.x, ga.y, ga.z, ga.w, gb.x, gb.y, gb.z, gb.w};
    float bt[8] = {ba.x, ba.y, ba.z, ba.w, bb.x, bb.y, bb.z, bb.w};

    short8 o8;
#pragma unroll
    for (int j = 0; j < 8; ++j)
        o8[j] = (short)f2bf((v[j] - mean) * rstd * gg[j] + bt[j]);
    *(short8*)&xr[c0] = o8;
}

// ---------------------------------------------------------------------------
// Workspace (MiB), overlays lifetime-checked (R1 layout):
//   [ 0, 4)  xbf            (alive whole run)
//   [ 4, 8)  Qbuf | hcbf    (Q dead after attn; hc dead after Wo)
//   [ 8,12)  Kbuf
//   [12,16)  Vtbuf
//   [16,32)  Opart (attn->merge) | y fp32 [16,24) | hidbf [24,28)
//   [32,32.5) lpart
//   [33,39.25) weights bf16
// ---------------------------------------------------------------------------
extern "C" void kernel_launch(void* const* d_in, const int* in_sizes, int n_in,
                              void* d_out, int out_size, void* d_ws, size_t ws_size,
                              hipStream_t stream)
{
    (void)in_sizes; (void)n_in; (void)out_size; (void)ws_size;
    const float* x   = (const float*)d_in[0];
    const float* Wq  = (const float*)d_in[1];
    const float* bq  = (const float*)d_in[2];
    const float* Wk  = (const float*)d_in[3];
    const float* bk  = (const float*)d_in[4];
    const float* Wv  = (const float*)d_in[5];
    const float* bv  = (const float*)d_in[6];
    const float* Wo  = (const float*)d_in[7];
    const float* bo  = (const float*)d_in[8];
    const float* g1  = (const float*)d_in[9];
    const float* be1 = (const float*)d_in[10];
    const float* W1  = (const float*)d_in[11];
    const float* b1  = (const float*)d_in[12];
    const float* W2  = (const float*)d_in[13];
    const float* b2  = (const float*)d_in[14];
    const float* g2  = (const float*)d_in[15];
    const float* be2 = (const float*)d_in[16];
    const float* Wp  = (const float*)d_in[17];
    const float* bp  = (const float*)d_in[18];

    char* wsb = (char*)d_ws;
    const size_t MB = 1024 * 1024;
    short* xbf   = (short*)(wsb + 0);
    short* Qbuf  = (short*)(wsb + 4 * MB);
    short* Kbuf  = (short*)(wsb + 8 * MB);
    short* Vtbuf = (short*)(wsb + 12 * MB);
    short* Opart = (short*)(wsb + 16 * MB);
    float* y     = (float*)(wsb + 16 * MB);   // overlay (disjoint lifetime)
    short* hidbf = (short*)(wsb + 24 * MB);   // overlay (disjoint lifetime)
    float* lpart = (float*)(wsb + 32 * MB);
    short* hcbf  = Qbuf;                       // overlay
    short* Wqt   = (short*)(wsb + 33 * MB);
    short* Wkt   = (short*)(wsb + 34 * MB);
    short* Wvt   = (short*)(wsb + 35 * MB);
    short* Wot   = (short*)(wsb + 36 * MB);
    short* W1t   = (short*)(wsb + 37 * MB);
    short* W2t   = (short*)(wsb + 38 * MB);
    short* Wpt   = (short*)(wsb + 39 * MB);

    prep_k<<<1056, 256, 0, stream>>>(Wq, Wk, Wv, Wo, W1, W2, Wp, x,
                                     Wqt, Wkt, Wvt, Wot, W1t, W2t, Wpt, xbf);

    for (int i = 0; i < 2; ++i) {
        const size_t wOff = (size_t)i * 262144;
        qkv_bf<<<dim3(24, 32), 256, 0, stream>>>(
            xbf, Wqt + wOff, Wkt + wOff, Wvt + wOff,
            bq + i * 512, bk + i * 512, bv + i * 512,
            Qbuf, Kbuf, Vtbuf);
        attn_mfma<<<dim3(8, 16, SPLIT), 256, 0, stream>>>(Qbuf, Kbuf, Vtbuf, Opart, lpart);
        merge_k<<<2048, 256, 0, stream>>>(Opart, lpart, hcbf);
        gemm_bf<<<dim3(8, 64), 256, 0, stream>>>(
            hcbf, Wot + wOff, bo + i * 512, y, MDIM, DDIM, DDIM, 0);
        addnorm_bf<<<1024, 256, 0, stream>>>(xbf, y, g1 + i * 512, be1 + i * 512);
        gemm_bf<<<dim3(8, 64), 256, 0, stream>>>(
            xbf, W1t + wOff, b1 + i * 512, hidbf, MDIM, DDIM, DDIM, 3);
        gemm_bf<<<dim3(8, 64), 256, 0, stream>>>(
            hidbf, W2t + wOff, b2 + i * 512, y, MDIM, DDIM, DDIM, 0);
        addnorm_bf<<<1024, 256, 0, stream>>>(xbf, y, g2 + i * 512, be2 + i * 512);
    }
    gemm_bf<<<dim3(4, 64), 256, 0, stream>>>(
        xbf, Wpt, bp, (float*)d_out, MDIM, TDIM, DDIM, 0);
}